// Round 1
// baseline (4797.393 us; speedup 1.0000x reference)
//
#include <hip/hip_runtime.h>
#include <math.h>

// Problem constants
#define BB 4
#define TT 2048
#define DD 1024
#define HH 4
#define DK 256
#define DV 256
// rows = B*T
#define RR 8192

// ---------------------------------------------------------------------------
// LayerNorm: one block (256 thr) per row of D=1024
// ---------------------------------------------------------------------------
__global__ __launch_bounds__(256) void ln_kernel(const float* __restrict__ x,
                                                 const float* __restrict__ w,
                                                 const float* __restrict__ b,
                                                 float* __restrict__ y) {
  int row = blockIdx.x;
  const float* xr = x + (size_t)row * DD;
  float* yr = y + (size_t)row * DD;
  int tid = threadIdx.x;

  float4 v = ((const float4*)xr)[tid];
  float s = v.x + v.y + v.z + v.w;
  float ss = v.x * v.x + v.y * v.y + v.z * v.z + v.w * v.w;
#pragma unroll
  for (int o = 32; o > 0; o >>= 1) {
    s += __shfl_down(s, o);
    ss += __shfl_down(ss, o);
  }
  __shared__ float ls[4], lss[4];
  int wid = tid >> 6;
  if ((tid & 63) == 0) { ls[wid] = s; lss[wid] = ss; }
  __syncthreads();
  float sum = ls[0] + ls[1] + ls[2] + ls[3];
  float sumsq = lss[0] + lss[1] + lss[2] + lss[3];
  float mu = sum * (1.0f / DD);
  float var = sumsq * (1.0f / DD) - mu * mu;
  float rs = rsqrtf(var + 1e-5f);

  float4 wv = ((const float4*)w)[tid];
  float4 bv = ((const float4*)b)[tid];
  float4 o;
  o.x = (v.x - mu) * rs * wv.x + bv.x;
  o.y = (v.y - mu) * rs * wv.y + bv.y;
  o.z = (v.z - mu) * rs * wv.z + bv.z;
  o.w = (v.w - mu) * rs * wv.w + bv.w;
  ((float4*)yr)[tid] = o;
}

// ---------------------------------------------------------------------------
// f32 GEMM: C[M,N] = A[M,K] @ B[K,N] (+epilogue)
// EPI: 0 = none, 1 = +bias, 2 = +bias then (leaky_relu)^2, 3 = +residual,
//      4 = +bias +residual
// 64x64 tile, BK=16, 256 threads, 4x4 per thread.
// ---------------------------------------------------------------------------
template <int EPI>
__global__ __launch_bounds__(256) void gemm_f32(const float* __restrict__ A,
                                                const float* __restrict__ B,
                                                const float* __restrict__ bias,
                                                const float* __restrict__ Res,
                                                float* __restrict__ C, int M,
                                                int N, int K) {
  __shared__ float As[16][68];  // [k][m]
  __shared__ float Bs[16][68];  // [k][n]
  int tid = threadIdx.x;
  int tx = tid & 15, ty = tid >> 4;
  int n0 = blockIdx.x * 64, m0 = blockIdx.y * 64;

  float acc[4][4] = {};

  for (int k0 = 0; k0 < K; k0 += 16) {
    // A tile: thread loads float4 along k. m = tid>>2 (0..63), k = (tid&3)*4
    {
      int m = tid >> 2;
      int kq = (tid & 3) * 4;
      float4 av = *(const float4*)&A[(size_t)(m0 + m) * K + k0 + kq];
      As[kq + 0][m] = av.x;
      As[kq + 1][m] = av.y;
      As[kq + 2][m] = av.z;
      As[kq + 3][m] = av.w;
    }
    // B tile: k = tid>>4 (0..15), n4 = (tid&15)*4
    {
      int k = tid >> 4;
      int n4 = (tid & 15) * 4;
      *(float4*)&Bs[k][n4] =
          *(const float4*)&B[(size_t)(k0 + k) * N + n0 + n4];
    }
    __syncthreads();
#pragma unroll
    for (int kk = 0; kk < 16; ++kk) {
      float a4[4], b4[4];
      *(float4*)a4 = *(const float4*)&As[kk][ty * 4];
      *(float4*)b4 = *(const float4*)&Bs[kk][tx * 4];
#pragma unroll
      for (int i = 0; i < 4; ++i)
#pragma unroll
        for (int j = 0; j < 4; ++j) acc[i][j] += a4[i] * b4[j];
    }
    __syncthreads();
  }

#pragma unroll
  for (int i = 0; i < 4; ++i) {
    int m = m0 + ty * 4 + i;
#pragma unroll
    for (int j = 0; j < 4; ++j) {
      int n = n0 + tx * 4 + j;
      float v = acc[i][j];
      if (EPI == 1 || EPI == 2 || EPI == 4) v += bias[n];
      if (EPI == 2) {
        float t = v > 0.0f ? v : 0.01f * v;
        v = t * t;
      }
      if (EPI == 3 || EPI == 4) v += Res[(size_t)m * N + n];
      C[(size_t)m * N + n] = v;
    }
  }
}

// ---------------------------------------------------------------------------
// Low-rank forget gate, fused: per row r,
//   tmp[16] = xn[r,:] @ Wgk1;  z[n] = tmp @ Wgk2[:,n] + bgk2[n]
//   egk[r,n] = exp(log_sigmoid(z)/16)
// One block (256 thr) per row.
// ---------------------------------------------------------------------------
__global__ __launch_bounds__(256) void gk_kernel(const float* __restrict__ xn,
                                                 const float* __restrict__ Wgk1,
                                                 const float* __restrict__ Wgk2,
                                                 const float* __restrict__ bgk2,
                                                 float* __restrict__ egk) {
  int row = blockIdx.x;
  const float* xr = xn + (size_t)row * DD;
  int tid = threadIdx.x;

  float t16[16];
#pragma unroll
  for (int j = 0; j < 16; ++j) t16[j] = 0.0f;

#pragma unroll
  for (int dd = 0; dd < 4; ++dd) {
    int d = tid + dd * 256;
    float xv = xr[d];
    const float4* wrow = (const float4*)(Wgk1 + (size_t)d * 16);
#pragma unroll
    for (int q = 0; q < 4; ++q) {
      float4 wq = wrow[q];
      t16[q * 4 + 0] += xv * wq.x;
      t16[q * 4 + 1] += xv * wq.y;
      t16[q * 4 + 2] += xv * wq.z;
      t16[q * 4 + 3] += xv * wq.w;
    }
  }
  // reduce each of 16 across wave (64 lanes)
#pragma unroll
  for (int j = 0; j < 16; ++j) {
    float s = t16[j];
#pragma unroll
    for (int o = 32; o > 0; o >>= 1) s += __shfl_down(s, o);
    t16[j] = s;
  }
  __shared__ float tmp[4][16];
  __shared__ float tf[16];
  int wid = tid >> 6;
  if ((tid & 63) == 0) {
#pragma unroll
    for (int j = 0; j < 16; ++j) tmp[wid][j] = t16[j];
  }
  __syncthreads();
  if (tid < 16) tf[tid] = tmp[0][tid] + tmp[1][tid] + tmp[2][tid] + tmp[3][tid];
  __syncthreads();

  float tl[16];
#pragma unroll
  for (int j = 0; j < 16; ++j) tl[j] = tf[j];

#pragma unroll
  for (int jj = 0; jj < 4; ++jj) {
    int n = tid * 4 + jj;
    float z = bgk2[n];
#pragma unroll
    for (int j = 0; j < 16; ++j) z += tl[j] * Wgk2[j * 1024 + n];
    // stable log-sigmoid
    float ls = fminf(z, 0.0f) - log1pf(expf(-fabsf(z)));
    egk[(size_t)row * 1024 + n] = expf(ls * (1.0f / 16.0f));
  }
}

// ---------------------------------------------------------------------------
// GLA scan. grid = B*H*16 blocks (vc = 16-wide dv chunk), 256 threads.
// thread: kg = tid&15 (owns k = kg*16..kg*16+15), vl = tid>>4 (one v col).
// State hs[16] in registers. Per step: h = h*egk + k*v; o += q*h; reduce over
// kg via shfl_xor (16-lane groups); lane kg==0 writes o.
// ---------------------------------------------------------------------------
__global__ __launch_bounds__(256) void gla_scan(const float* __restrict__ q,
                                                const float* __restrict__ k,
                                                const float* __restrict__ v,
                                                const float* __restrict__ egk,
                                                float* __restrict__ o) {
  int bid = blockIdx.x;
  int vc = bid & 15;
  int bh = bid >> 4;
  int b = bh >> 2, h = bh & 3;
  int tid = threadIdx.x;
  int kg = tid & 15;
  int vl = tid >> 4;
  int vcol = vc * 16 + vl;

  size_t base = (size_t)b * TT * 1024 + h * 256;
  const float* qb = q + base + kg * 16;
  const float* kb = k + base + kg * 16;
  const float* gb = egk + base + kg * 16;
  const float* vb = v + base + vcol;
  float* ob = o + base + vcol;

  float hs[16];
#pragma unroll
  for (int i = 0; i < 16; ++i) hs[i] = 0.0f;

  const float scale = 0.0625f;  // DK^-0.5

  for (int t = 0; t < TT; ++t) {
    size_t off = (size_t)t * 1024;
    float qv[16], kv[16], gv[16];
    *(float4*)&qv[0] = *(const float4*)(qb + off);
    *(float4*)&qv[4] = *(const float4*)(qb + off + 4);
    *(float4*)&qv[8] = *(const float4*)(qb + off + 8);
    *(float4*)&qv[12] = *(const float4*)(qb + off + 12);
    *(float4*)&kv[0] = *(const float4*)(kb + off);
    *(float4*)&kv[4] = *(const float4*)(kb + off + 4);
    *(float4*)&kv[8] = *(const float4*)(kb + off + 8);
    *(float4*)&kv[12] = *(const float4*)(kb + off + 12);
    *(float4*)&gv[0] = *(const float4*)(gb + off);
    *(float4*)&gv[4] = *(const float4*)(gb + off + 4);
    *(float4*)&gv[8] = *(const float4*)(gb + off + 8);
    *(float4*)&gv[12] = *(const float4*)(gb + off + 12);
    float vv = vb[off];

    float op = 0.0f;
#pragma unroll
    for (int i = 0; i < 16; ++i) {
      hs[i] = hs[i] * gv[i] + kv[i] * vv;
      op += qv[i] * hs[i];
    }
    op += __shfl_xor(op, 1);
    op += __shfl_xor(op, 2);
    op += __shfl_xor(op, 4);
    op += __shfl_xor(op, 8);
    if (kg == 0) ob[off] = op * scale;
  }
}

// ---------------------------------------------------------------------------
// Gated RMSNorm: one block per (row,h) group of 256 elems.
//   og = rmsnorm(o)*rms_w * (g*sigmoid(g))
// ---------------------------------------------------------------------------
__global__ __launch_bounds__(256) void grms_kernel(const float* __restrict__ o,
                                                   const float* __restrict__ g,
                                                   const float* __restrict__ rw,
                                                   float* __restrict__ og) {
  size_t base = (size_t)blockIdx.x * 256;
  int tid = threadIdx.x;
  float ov = o[base + tid];
  float s = ov * ov;
#pragma unroll
  for (int off = 32; off > 0; off >>= 1) s += __shfl_down(s, off);
  __shared__ float red[4];
  int wid = tid >> 6;
  if ((tid & 63) == 0) red[wid] = s;
  __syncthreads();
  float ms = (red[0] + red[1] + red[2] + red[3]) * (1.0f / 256.0f);
  float gv = g[base + tid];
  float sw = gv / (1.0f + expf(-gv));
  og[base + tid] = ov * rsqrtf(ms + 1e-5f) * rw[tid] * sw;
}

// ---------------------------------------------------------------------------
extern "C" void kernel_launch(void* const* d_in, const int* in_sizes, int n_in,
                              void* d_out, int out_size, void* d_ws,
                              size_t ws_size, hipStream_t stream) {
  const float* x = (const float*)d_in[0];
  const float* ln1_w = (const float*)d_in[1];
  const float* ln1_b = (const float*)d_in[2];
  const float* Wq = (const float*)d_in[3];
  const float* Wk = (const float*)d_in[4];
  const float* Wv = (const float*)d_in[5];
  const float* Wg = (const float*)d_in[6];
  const float* Wgk1 = (const float*)d_in[7];
  const float* Wgk2 = (const float*)d_in[8];
  const float* bgk2 = (const float*)d_in[9];
  const float* rms_w = (const float*)d_in[10];
  const float* Wo = (const float*)d_in[11];
  const float* ln2_w = (const float*)d_in[12];
  const float* ln2_b = (const float*)d_in[13];
  const float* W1 = (const float*)d_in[14];
  const float* b1 = (const float*)d_in[15];
  const float* W2 = (const float*)d_in[16];
  const float* b2 = (const float*)d_in[17];
  float* out = (float*)d_out;

  const size_t S = (size_t)RR * DD;  // 8.4M floats
  float* f0 = (float*)d_ws;          // xn / xn2
  float* f1 = f0 + S;                // q / og
  float* f2 = f1 + S;                // k / x1
  float* f3 = f2 + S;                // v / mlp hidden (spans f3..f5)
  float* f4 = f3 + S;                // g
  float* f5 = f4 + S;                // egk
  float* f6 = f5 + S;                // o (scan out)

  dim3 blk(256);

  // 1. xn = LN(x)
  ln_kernel<<<RR, blk, 0, stream>>>(x, ln1_w, ln1_b, f0);

  // 2. q,k,v,g projections
  dim3 g1024(1024 / 64, RR / 64);
  gemm_f32<0><<<g1024, blk, 0, stream>>>(f0, Wq, nullptr, nullptr, f1, RR, 1024, 1024);
  gemm_f32<0><<<g1024, blk, 0, stream>>>(f0, Wk, nullptr, nullptr, f2, RR, 1024, 1024);
  gemm_f32<0><<<g1024, blk, 0, stream>>>(f0, Wv, nullptr, nullptr, f3, RR, 1024, 1024);
  gemm_f32<0><<<g1024, blk, 0, stream>>>(f0, Wg, nullptr, nullptr, f4, RR, 1024, 1024);

  // 3. egk = exp(log_sigmoid(low-rank gate)/16)
  gk_kernel<<<RR, blk, 0, stream>>>(f0, Wgk1, Wgk2, bgk2, f5);

  // 4. GLA scan -> o (f6)
  gla_scan<<<BB * HH * 16, blk, 0, stream>>>(f1, f2, f3, f5, f6);

  // 5. og = rmsnorm(o)*rms_w * swish(g) -> f1
  grms_kernel<<<RR * HH, blk, 0, stream>>>(f6, f4, rms_w, f1);

  // 6. x1 = x + og @ Wo -> f2
  gemm_f32<3><<<g1024, blk, 0, stream>>>(f1, Wo, nullptr, x, f2, RR, 1024, 1024);

  // 7. xn2 = LN(x1) -> f0
  ln_kernel<<<RR, blk, 0, stream>>>(f2, ln2_w, ln2_b, f0);

  // 8. h = (leaky_relu(xn2@W1 + b1))^2 -> f3 (3S region)
  dim3 g3072(3072 / 64, RR / 64);
  gemm_f32<2><<<g3072, blk, 0, stream>>>(f0, W1, b1, nullptr, f3, RR, 3072, 1024);

  // 9. out = x1 + h @ W2 + b2
  gemm_f32<4><<<g1024, blk, 0, stream>>>(f3, W2, b2, f2, out, RR, 1024, 3072);
}

// Round 2
// 4423.984 us; speedup vs baseline: 1.0844x; 1.0844x over previous
//
#include <hip/hip_runtime.h>
#include <math.h>

// Problem constants
#define BB 4
#define TT 2048
#define DD 1024
#define HH 4
#define DK 256
#define DV 256
#define RR 8192
#define CHK 64
#define NCHK 32

// ---------------------------------------------------------------------------
// LayerNorm: one block (256 thr) per row of D=1024
// ---------------------------------------------------------------------------
__global__ __launch_bounds__(256) void ln_kernel(const float* __restrict__ x,
                                                 const float* __restrict__ w,
                                                 const float* __restrict__ b,
                                                 float* __restrict__ y) {
  int row = blockIdx.x;
  const float* xr = x + (size_t)row * DD;
  float* yr = y + (size_t)row * DD;
  int tid = threadIdx.x;

  float4 v = ((const float4*)xr)[tid];
  float s = v.x + v.y + v.z + v.w;
  float ss = v.x * v.x + v.y * v.y + v.z * v.z + v.w * v.w;
#pragma unroll
  for (int o = 32; o > 0; o >>= 1) {
    s += __shfl_down(s, o);
    ss += __shfl_down(ss, o);
  }
  __shared__ float ls[4], lss[4];
  int wid = tid >> 6;
  if ((tid & 63) == 0) { ls[wid] = s; lss[wid] = ss; }
  __syncthreads();
  float sum = ls[0] + ls[1] + ls[2] + ls[3];
  float sumsq = lss[0] + lss[1] + lss[2] + lss[3];
  float mu = sum * (1.0f / DD);
  float var = sumsq * (1.0f / DD) - mu * mu;
  float rs = rsqrtf(var + 1e-5f);

  float4 wv = ((const float4*)w)[tid];
  float4 bv = ((const float4*)b)[tid];
  float4 o;
  o.x = (v.x - mu) * rs * wv.x + bv.x;
  o.y = (v.y - mu) * rs * wv.y + bv.y;
  o.z = (v.z - mu) * rs * wv.z + bv.z;
  o.w = (v.w - mu) * rs * wv.w + bv.w;
  ((float4*)yr)[tid] = o;
}

// ---------------------------------------------------------------------------
// f32 GEMM: C[M,N] = A[M,K] @ B[K,N] (+epilogue)
// EPI: 0 none, 1 +bias, 2 +bias,(leaky)^2, 3 +res, 4 +bias+res
// ---------------------------------------------------------------------------
template <int EPI>
__global__ __launch_bounds__(256) void gemm_f32(const float* __restrict__ A,
                                                const float* __restrict__ B,
                                                const float* __restrict__ bias,
                                                const float* __restrict__ Res,
                                                float* __restrict__ C, int M,
                                                int N, int K) {
  __shared__ float As[16][68];
  __shared__ float Bs[16][68];
  int tid = threadIdx.x;
  int tx = tid & 15, ty = tid >> 4;
  int n0 = blockIdx.x * 64, m0 = blockIdx.y * 64;

  float acc[4][4] = {};

  for (int k0 = 0; k0 < K; k0 += 16) {
    {
      int m = tid >> 2;
      int kq = (tid & 3) * 4;
      float4 av = *(const float4*)&A[(size_t)(m0 + m) * K + k0 + kq];
      As[kq + 0][m] = av.x;
      As[kq + 1][m] = av.y;
      As[kq + 2][m] = av.z;
      As[kq + 3][m] = av.w;
    }
    {
      int k = tid >> 4;
      int n4 = (tid & 15) * 4;
      *(float4*)&Bs[k][n4] = *(const float4*)&B[(size_t)(k0 + k) * N + n0 + n4];
    }
    __syncthreads();
#pragma unroll
    for (int kk = 0; kk < 16; ++kk) {
      float a4[4], b4[4];
      *(float4*)a4 = *(const float4*)&As[kk][ty * 4];
      *(float4*)b4 = *(const float4*)&Bs[kk][tx * 4];
#pragma unroll
      for (int i = 0; i < 4; ++i)
#pragma unroll
        for (int j = 0; j < 4; ++j) acc[i][j] += a4[i] * b4[j];
    }
    __syncthreads();
  }

#pragma unroll
  for (int i = 0; i < 4; ++i) {
    int m = m0 + ty * 4 + i;
#pragma unroll
    for (int j = 0; j < 4; ++j) {
      int n = n0 + tx * 4 + j;
      float v = acc[i][j];
      if (EPI == 1 || EPI == 2 || EPI == 4) v += bias[n];
      if (EPI == 2) {
        float t = v > 0.0f ? v : 0.01f * v;
        v = t * t;
      }
      if (EPI == 3 || EPI == 4) v += Res[(size_t)m * N + n];
      C[(size_t)m * N + n] = v;
    }
  }
}

// ---------------------------------------------------------------------------
// Low-rank forget gate -> LOG gate gk = log_sigmoid(z)/16  (per row)
// ---------------------------------------------------------------------------
__global__ __launch_bounds__(256) void gk_kernel(const float* __restrict__ xn,
                                                 const float* __restrict__ Wgk1,
                                                 const float* __restrict__ Wgk2,
                                                 const float* __restrict__ bgk2,
                                                 float* __restrict__ gk) {
  int row = blockIdx.x;
  const float* xr = xn + (size_t)row * DD;
  int tid = threadIdx.x;

  float t16[16];
#pragma unroll
  for (int j = 0; j < 16; ++j) t16[j] = 0.0f;

#pragma unroll
  for (int dd = 0; dd < 4; ++dd) {
    int d = tid + dd * 256;
    float xv = xr[d];
    const float4* wrow = (const float4*)(Wgk1 + (size_t)d * 16);
#pragma unroll
    for (int q = 0; q < 4; ++q) {
      float4 wq = wrow[q];
      t16[q * 4 + 0] += xv * wq.x;
      t16[q * 4 + 1] += xv * wq.y;
      t16[q * 4 + 2] += xv * wq.z;
      t16[q * 4 + 3] += xv * wq.w;
    }
  }
#pragma unroll
  for (int j = 0; j < 16; ++j) {
    float s = t16[j];
#pragma unroll
    for (int o = 32; o > 0; o >>= 1) s += __shfl_down(s, o);
    t16[j] = s;
  }
  __shared__ float tmp[4][16];
  __shared__ float tf[16];
  int wid = tid >> 6;
  if ((tid & 63) == 0) {
#pragma unroll
    for (int j = 0; j < 16; ++j) tmp[wid][j] = t16[j];
  }
  __syncthreads();
  if (tid < 16) tf[tid] = tmp[0][tid] + tmp[1][tid] + tmp[2][tid] + tmp[3][tid];
  __syncthreads();

  float tl[16];
#pragma unroll
  for (int j = 0; j < 16; ++j) tl[j] = tf[j];

#pragma unroll
  for (int jj = 0; jj < 4; ++jj) {
    int n = tid * 4 + jj;
    float z = bgk2[n];
#pragma unroll
    for (int j = 0; j < 16; ++j) z += tl[j] * Wgk2[j * 1024 + n];
    float ls = fminf(z, 0.0f) - log1pf(expf(-fabsf(z)));
    gk[(size_t)row * 1024 + n] = ls * (1.0f / 16.0f);
  }
}

// ---------------------------------------------------------------------------
// gate_chunk: per (b,h,chunk) block, 256 thr (one dk each).
// pass1: cum_t = sum gk; q <- q*exp(cum)*scale (in place); k <- k*exp(-cum).
// pass2: khat_t = ktilde_t * exp(bC)  (written over gk buffer, same ptr).
// Also writes ebC = exp(bC).
// ---------------------------------------------------------------------------
__global__ __launch_bounds__(256) void gate_chunk(float* __restrict__ gk_khat,
                                                  float* __restrict__ q,
                                                  float* __restrict__ k,
                                                  float* __restrict__ ebC) {
  int bid = blockIdx.x;
  int c = bid & 31;
  int h = (bid >> 5) & 3;
  int b = bid >> 7;
  int tid = threadIdx.x;
  size_t base = ((size_t)b * TT + c * CHK) * 1024 + h * 256 + tid;

  const float scale = 0.0625f;
  float cum = 0.0f;
  for (int t = 0; t < CHK; ++t) {
    size_t a = base + (size_t)t * 1024;
    cum += gk_khat[a];
    q[a] = q[a] * expf(cum) * scale;
    k[a] = k[a] * expf(-cum);
  }
  float ebv = expf(cum);
  ebC[((b * 4 + h) * NCHK + c) * 256 + tid] = ebv;
  for (int t = 0; t < CHK; ++t) {
    size_t a = base + (size_t)t * 1024;
    gk_khat[a] = k[a] * ebv;
  }
}

// ---------------------------------------------------------------------------
// intra_kernel: per (b,h,chunk): S = causal(qt @ kt^T) [64x64, K=256],
// then O_intra = S @ V [64x256, K=64] -> o
// ---------------------------------------------------------------------------
__global__ __launch_bounds__(256) void intra_kernel(const float* __restrict__ qt,
                                                    const float* __restrict__ kt,
                                                    const float* __restrict__ v,
                                                    float* __restrict__ o) {
  __shared__ float As[16][68];
  __shared__ float Bs[16][68];
  __shared__ float Ss[64][73];
  __shared__ float Vs[64][68];
  int bid = blockIdx.x;
  int c = bid & 31;
  int h = (bid >> 5) & 3;
  int b = bid >> 7;
  size_t rowbase = ((size_t)b * TT + c * CHK) * 1024 + h * 256;
  int tid = threadIdx.x;
  int tx = tid & 15, ty = tid >> 4;

  float acc[4][4] = {};
  for (int k0 = 0; k0 < 256; k0 += 16) {
    {
      int t = tid >> 2;
      int kq = (tid & 3) * 4;
      float4 av = *(const float4*)&qt[rowbase + (size_t)t * 1024 + k0 + kq];
      As[kq + 0][t] = av.x;
      As[kq + 1][t] = av.y;
      As[kq + 2][t] = av.z;
      As[kq + 3][t] = av.w;
      float4 bv = *(const float4*)&kt[rowbase + (size_t)t * 1024 + k0 + kq];
      Bs[kq + 0][t] = bv.x;
      Bs[kq + 1][t] = bv.y;
      Bs[kq + 2][t] = bv.z;
      Bs[kq + 3][t] = bv.w;
    }
    __syncthreads();
#pragma unroll
    for (int kk = 0; kk < 16; ++kk) {
      float a4[4], b4[4];
      *(float4*)a4 = *(const float4*)&As[kk][ty * 4];
      *(float4*)b4 = *(const float4*)&Bs[kk][tx * 4];
#pragma unroll
      for (int i = 0; i < 4; ++i)
#pragma unroll
        for (int j = 0; j < 4; ++j) acc[i][j] += a4[i] * b4[j];
    }
    __syncthreads();
  }
  // causal mask (keep s<=t) and park S in LDS
#pragma unroll
  for (int i = 0; i < 4; ++i) {
    int t = ty * 4 + i;
#pragma unroll
    for (int j = 0; j < 4; ++j) {
      int s = tx * 4 + j;
      Ss[t][s] = (s <= t) ? acc[i][j] : 0.0f;
    }
  }
  __syncthreads();

  // O = S @ V in four 64-col panels
  for (int nt = 0; nt < 4; ++nt) {
#pragma unroll
    for (int i = 0; i < 4; ++i) {
      int s = (tid >> 4) + i * 16;
      int c4 = (tid & 15) * 4;
      *(float4*)&Vs[s][c4] =
          *(const float4*)&v[rowbase + (size_t)s * 1024 + nt * 64 + c4];
    }
    __syncthreads();
    float acc2[4][4] = {};
    for (int s = 0; s < 64; ++s) {
      float a4[4], b4[4];
#pragma unroll
      for (int i = 0; i < 4; ++i) a4[i] = Ss[ty * 4 + i][s];
      *(float4*)b4 = *(const float4*)&Vs[s][tx * 4];
#pragma unroll
      for (int i = 0; i < 4; ++i)
#pragma unroll
        for (int j = 0; j < 4; ++j) acc2[i][j] += a4[i] * b4[j];
    }
#pragma unroll
    for (int i = 0; i < 4; ++i)
#pragma unroll
      for (int j = 0; j < 4; ++j)
        o[rowbase + (size_t)(ty * 4 + i) * 1024 + nt * 64 + tx * 4 + j] =
            acc2[i][j];
    __syncthreads();
  }
}

// ---------------------------------------------------------------------------
// inter_scan: grid = B*H*16 (vc = 16-wide dv chunk), 256 thr.
// thread: kg = tid&15 (dk block of 16), vl = tid>>4 (one dv col).
// Per chunk: o[t,dv] += qt[t,:]·h (h frozen), U += khat^T v; then
// h = ebC*h + U. Serial depth = 32 chunks; inner 64 steps independent.
// ---------------------------------------------------------------------------
__global__ __launch_bounds__(256) void inter_scan(const float* __restrict__ qt,
                                                  const float* __restrict__ khat,
                                                  const float* __restrict__ v,
                                                  const float* __restrict__ ebC,
                                                  float* __restrict__ o) {
  int bid = blockIdx.x;
  int vc = bid & 15;
  int bh = bid >> 4;
  int b = bh >> 2, h = bh & 3;
  int tid = threadIdx.x;
  int kg = tid & 15;
  int vl = tid >> 4;
  int vcol = vc * 16 + vl;

  size_t base = (size_t)b * TT * 1024 + h * 256;
  const float* qb = qt + base + kg * 16;
  const float* kb = khat + base + kg * 16;
  const float* vb = v + base + vcol;
  float* ob = o + base + vcol;
  const float* ebb = ebC + (size_t)(b * 4 + h) * NCHK * 256 + kg * 16;

  float hs[16];
#pragma unroll
  for (int i = 0; i < 16; ++i) hs[i] = 0.0f;

  for (int c = 0; c < NCHK; ++c) {
    float us[16];
#pragma unroll
    for (int i = 0; i < 16; ++i) us[i] = 0.0f;

    for (int t = 0; t < CHK; ++t) {
      size_t off = (size_t)(c * CHK + t) * 1024;
      float qv[16], kv[16];
      *(float4*)&qv[0] = *(const float4*)(qb + off);
      *(float4*)&qv[4] = *(const float4*)(qb + off + 4);
      *(float4*)&qv[8] = *(const float4*)(qb + off + 8);
      *(float4*)&qv[12] = *(const float4*)(qb + off + 12);
      *(float4*)&kv[0] = *(const float4*)(kb + off);
      *(float4*)&kv[4] = *(const float4*)(kb + off + 4);
      *(float4*)&kv[8] = *(const float4*)(kb + off + 8);
      *(float4*)&kv[12] = *(const float4*)(kb + off + 12);
      float vv = vb[off];

      float op = 0.0f;
#pragma unroll
      for (int i = 0; i < 16; ++i) {
        op += qv[i] * hs[i];
        us[i] += kv[i] * vv;
      }
      op += __shfl_xor(op, 1);
      op += __shfl_xor(op, 2);
      op += __shfl_xor(op, 4);
      op += __shfl_xor(op, 8);
      if (kg == 0) ob[off] += op;
    }

    float eb[16];
    const float* ep = ebb + (size_t)c * 256;
    *(float4*)&eb[0] = *(const float4*)(ep);
    *(float4*)&eb[4] = *(const float4*)(ep + 4);
    *(float4*)&eb[8] = *(const float4*)(ep + 8);
    *(float4*)&eb[12] = *(const float4*)(ep + 12);
#pragma unroll
    for (int i = 0; i < 16; ++i) hs[i] = eb[i] * hs[i] + us[i];
  }
}

// ---------------------------------------------------------------------------
// Gated RMSNorm
// ---------------------------------------------------------------------------
__global__ __launch_bounds__(256) void grms_kernel(const float* __restrict__ o,
                                                   const float* __restrict__ g,
                                                   const float* __restrict__ rw,
                                                   float* __restrict__ og) {
  size_t base = (size_t)blockIdx.x * 256;
  int tid = threadIdx.x;
  float ov = o[base + tid];
  float s = ov * ov;
#pragma unroll
  for (int off = 32; off > 0; off >>= 1) s += __shfl_down(s, off);
  __shared__ float red[4];
  int wid = tid >> 6;
  if ((tid & 63) == 0) red[wid] = s;
  __syncthreads();
  float ms = (red[0] + red[1] + red[2] + red[3]) * (1.0f / 256.0f);
  float gv = g[base + tid];
  float sw = gv / (1.0f + expf(-gv));
  og[base + tid] = ov * rsqrtf(ms + 1e-5f) * rw[tid] * sw;
}

// ---------------------------------------------------------------------------
extern "C" void kernel_launch(void* const* d_in, const int* in_sizes, int n_in,
                              void* d_out, int out_size, void* d_ws,
                              size_t ws_size, hipStream_t stream) {
  const float* x = (const float*)d_in[0];
  const float* ln1_w = (const float*)d_in[1];
  const float* ln1_b = (const float*)d_in[2];
  const float* Wq = (const float*)d_in[3];
  const float* Wk = (const float*)d_in[4];
  const float* Wv = (const float*)d_in[5];
  const float* Wg = (const float*)d_in[6];
  const float* Wgk1 = (const float*)d_in[7];
  const float* Wgk2 = (const float*)d_in[8];
  const float* bgk2 = (const float*)d_in[9];
  const float* rms_w = (const float*)d_in[10];
  const float* Wo = (const float*)d_in[11];
  const float* ln2_w = (const float*)d_in[12];
  const float* ln2_b = (const float*)d_in[13];
  const float* W1 = (const float*)d_in[14];
  const float* b1 = (const float*)d_in[15];
  const float* W2 = (const float*)d_in[16];
  const float* b2 = (const float*)d_in[17];
  float* out = (float*)d_out;

  const size_t S = (size_t)RR * DD;
  float* f0 = (float*)d_ws;  // xn ; ebC (after gemms) ; xn2 (late)
  float* f1 = f0 + S;        // q/q~ ; og (late)
  float* f2 = f1 + S;        // k/k~ ; x1 (late)
  float* f3 = f2 + S;        // v ; mlp hidden (f3..f5, late)
  float* f4 = f3 + S;        // g
  float* f5 = f4 + S;        // gk -> khat
  float* f6 = f5 + S;        // o

  dim3 blk(256);

  // 1. xn = LN(x)
  ln_kernel<<<RR, blk, 0, stream>>>(x, ln1_w, ln1_b, f0);

  // 2. projections
  dim3 g1024(1024 / 64, RR / 64);
  gemm_f32<0><<<g1024, blk, 0, stream>>>(f0, Wq, nullptr, nullptr, f1, RR, 1024, 1024);
  gemm_f32<0><<<g1024, blk, 0, stream>>>(f0, Wk, nullptr, nullptr, f2, RR, 1024, 1024);
  gemm_f32<0><<<g1024, blk, 0, stream>>>(f0, Wv, nullptr, nullptr, f3, RR, 1024, 1024);
  gemm_f32<0><<<g1024, blk, 0, stream>>>(f0, Wg, nullptr, nullptr, f4, RR, 1024, 1024);

  // 3. gk (log) -> f5
  gk_kernel<<<RR, blk, 0, stream>>>(f0, Wgk1, Wgk2, bgk2, f5);

  // 4. chunked gate transforms (xn in f0 now dead -> reuse f0 head for ebC)
  float* ebC = f0;  // 4*4*32*256 floats = 2MB, dead before xn2 is written
  gate_chunk<<<BB * HH * NCHK, blk, 0, stream>>>(f5, f1, f2, ebC);

  // 5. intra-chunk attention -> f6
  intra_kernel<<<BB * HH * NCHK, blk, 0, stream>>>(f1, f2, f3, f6);

  // 6. inter-chunk scan (adds into f6)
  inter_scan<<<BB * HH * 16, blk, 0, stream>>>(f1, f5, f3, ebC, f6);

  // 7. og = gated rmsnorm -> f1
  grms_kernel<<<RR * HH, blk, 0, stream>>>(f6, f4, rms_w, f1);

  // 8. x1 = x + og @ Wo -> f2
  gemm_f32<3><<<g1024, blk, 0, stream>>>(f1, Wo, nullptr, x, f2, RR, 1024, 1024);

  // 9. xn2 = LN(x1) -> f0
  ln_kernel<<<RR, blk, 0, stream>>>(f2, ln2_w, ln2_b, f0);

  // 10. h = (leaky_relu(xn2@W1+b1))^2 -> f3 (spans f3..f5, all dead)
  dim3 g3072(3072 / 64, RR / 64);
  gemm_f32<2><<<g3072, blk, 0, stream>>>(f0, W1, b1, nullptr, f3, RR, 3072, 1024);

  // 11. out = x1 + h @ W2 + b2
  gemm_f32<4><<<g1024, blk, 0, stream>>>(f3, W2, b2, f2, out, RR, 1024, 3072);
}

// Round 4
// 697.307 us; speedup vs baseline: 6.8799x; 6.3444x over previous
//
#include <hip/hip_runtime.h>
#include <math.h>

// Problem constants
#define BB 4
#define TT 2048
#define DD 1024
#define HH 4
#define DK 256
#define DV 256
#define RR 8192
#define CHK 64
#define NCHK 32

typedef __bf16 bf16x8 __attribute__((ext_vector_type(8)));
typedef float f32x4 __attribute__((ext_vector_type(4)));

static __device__ inline unsigned short f2bf(float f) {
  unsigned int u = __float_as_uint(f);
  unsigned int r = (u + 0x7fffu + ((u >> 16) & 1u)) >> 16;
  return (unsigned short)r;
}
static __device__ inline float bf2f(unsigned short h) {
  return __uint_as_float(((unsigned int)h) << 16);
}

// ---------------------------------------------------------------------------
// LayerNorm: one block (256 thr) per row of D=1024. f32 in -> bf16 out.
// ---------------------------------------------------------------------------
__global__ __launch_bounds__(256) void ln_kernel(const float* __restrict__ x,
                                                 const float* __restrict__ w,
                                                 const float* __restrict__ b,
                                                 unsigned short* __restrict__ yb) {
  int row = blockIdx.x;
  const float* xr = x + (size_t)row * DD;
  unsigned short* ybr = yb + (size_t)row * DD;
  int tid = threadIdx.x;

  float4 v = ((const float4*)xr)[tid];
  float s = v.x + v.y + v.z + v.w;
  float ss = v.x * v.x + v.y * v.y + v.z * v.z + v.w * v.w;
#pragma unroll
  for (int o = 32; o > 0; o >>= 1) {
    s += __shfl_down(s, o);
    ss += __shfl_down(ss, o);
  }
  __shared__ float ls[4], lss[4];
  int wid = tid >> 6;
  if ((tid & 63) == 0) { ls[wid] = s; lss[wid] = ss; }
  __syncthreads();
  float sum = ls[0] + ls[1] + ls[2] + ls[3];
  float sumsq = lss[0] + lss[1] + lss[2] + lss[3];
  float mu = sum * (1.0f / DD);
  float var = sumsq * (1.0f / DD) - mu * mu;
  float rs = rsqrtf(var + 1e-5f);

  float4 wv = ((const float4*)w)[tid];
  float4 bv = ((const float4*)b)[tid];
  ushort4 ob;
  ob.x = f2bf((v.x - mu) * rs * wv.x + bv.x);
  ob.y = f2bf((v.y - mu) * rs * wv.y + bv.y);
  ob.z = f2bf((v.z - mu) * rs * wv.z + bv.z);
  ob.w = f2bf((v.w - mu) * rs * wv.w + bv.w);
  ((ushort4*)ybr)[tid] = ob;
}

// ---------------------------------------------------------------------------
// Weight transpose + cast: W [K,N] f32 -> Wt [N,K] bf16
// ---------------------------------------------------------------------------
__global__ __launch_bounds__(256) void transpose_cast(const float* __restrict__ W,
                                                      unsigned short* __restrict__ Wt,
                                                      int K, int N) {
  __shared__ float t[32][33];
  int k0 = blockIdx.y * 32, n0 = blockIdx.x * 32;
  int tid = threadIdx.x;
  int tx = tid & 31, ty = tid >> 5;  // ty 0..7
#pragma unroll
  for (int i = 0; i < 4; ++i)
    t[ty + i * 8][tx] = W[(size_t)(k0 + ty + i * 8) * N + n0 + tx];
  __syncthreads();
#pragma unroll
  for (int i = 0; i < 4; ++i)
    Wt[(size_t)(n0 + ty + i * 8) * K + k0 + tx] = f2bf(t[tx][ty + i * 8]);
}

// ---------------------------------------------------------------------------
// bf16 MFMA GEMM: C[M,N] = A[M,K] @ Bt[N,K]^T  (+epilogue)
// EPI: 0 none, 2 +bias,(leaky)^2, 3 +res, 4 +bias+res.  OUTBF: bf16 vs f32 C.
// 128x128 tile, BK=32, 4 waves (2x2 of 64x64), mfma_f32_16x16x32_bf16.
// ---------------------------------------------------------------------------
#define LDP 40  // padded LDS row (bf16 elems); 80B rows keep 16B alignment

template <int EPI, int OUTBF>
__global__ __launch_bounds__(256) void gemm_bf16(
    const unsigned short* __restrict__ A,   // [M,K] bf16
    const unsigned short* __restrict__ Bt,  // [N,K] bf16
    const float* __restrict__ bias, const float* __restrict__ Res,
    void* __restrict__ Cv, int M, int N, int K) {
  __shared__ unsigned short As[128 * LDP];
  __shared__ unsigned short Bs[128 * LDP];
  int tid = threadIdx.x;
  int m0 = blockIdx.y * 128, n0 = blockIdx.x * 128;
  int lane = tid & 63;
  int wid = tid >> 6;
  int wm = (wid >> 1) * 64, wn = (wid & 1) * 64;

  f32x4 acc[4][4] = {};

  int srow = tid >> 2;       // 0..63
  int skq = (tid & 3) * 8;   // bf16 offset along k
  const unsigned short* Ap = A + (size_t)(m0 + srow) * K + skq;
  const unsigned short* Bp = Bt + (size_t)(n0 + srow) * K + skq;

  int fr = lane & 15, fk = (lane >> 4) * 8;

  for (int k0 = 0; k0 < K; k0 += 32) {
    bf16x8 a0 = *(const bf16x8*)(Ap + k0);
    bf16x8 a1 = *(const bf16x8*)(Ap + (size_t)64 * K + k0);
    bf16x8 b0 = *(const bf16x8*)(Bp + k0);
    bf16x8 b1 = *(const bf16x8*)(Bp + (size_t)64 * K + k0);
    __syncthreads();
    *(bf16x8*)&As[srow * LDP + skq] = a0;
    *(bf16x8*)&As[(srow + 64) * LDP + skq] = a1;
    *(bf16x8*)&Bs[srow * LDP + skq] = b0;
    *(bf16x8*)&Bs[(srow + 64) * LDP + skq] = b1;
    __syncthreads();

    bf16x8 af[4], bfr[4];
#pragma unroll
    for (int i = 0; i < 4; ++i) {
      af[i] = *(const bf16x8*)&As[(wm + i * 16 + fr) * LDP + fk];
      bfr[i] = *(const bf16x8*)&Bs[(wn + i * 16 + fr) * LDP + fk];
    }
#pragma unroll
    for (int i = 0; i < 4; ++i)
#pragma unroll
      for (int j = 0; j < 4; ++j)
        acc[i][j] = __builtin_amdgcn_mfma_f32_16x16x32_bf16(af[i], bfr[j],
                                                            acc[i][j], 0, 0, 0);
  }

  // epilogue: C/D layout col=lane&15, row=(lane>>4)*4+r  [verified m89/m91]
  int col = lane & 15;
  int rbase = (lane >> 4) * 4;
#pragma unroll
  for (int i = 0; i < 4; ++i) {
#pragma unroll
    for (int j = 0; j < 4; ++j) {
      int n = n0 + wn + j * 16 + col;
      float bv = (EPI == 2 || EPI == 4) ? bias[n] : 0.0f;
#pragma unroll
      for (int r = 0; r < 4; ++r) {
        int m = m0 + wm + i * 16 + rbase + r;
        float vv = acc[i][j][r] + bv;
        if (EPI == 2) {
          float t = vv > 0.0f ? vv : 0.01f * vv;
          vv = t * t;
        }
        if (EPI == 3 || EPI == 4) vv += Res[(size_t)m * N + n];
        if (OUTBF)
          ((unsigned short*)Cv)[(size_t)m * N + n] = f2bf(vv);
        else
          ((float*)Cv)[(size_t)m * N + n] = vv;
      }
    }
  }
}

// ---------------------------------------------------------------------------
// Low-rank forget gate -> LOG gate gk = log_sigmoid(z)/16 (bf16 in/out)
// ---------------------------------------------------------------------------
__global__ __launch_bounds__(256) void gk_kernel(const unsigned short* __restrict__ xn,
                                                 const float* __restrict__ Wgk1,
                                                 const float* __restrict__ Wgk2,
                                                 const float* __restrict__ bgk2,
                                                 unsigned short* __restrict__ gk) {
  int row = blockIdx.x;
  const unsigned short* xr = xn + (size_t)row * DD;
  int tid = threadIdx.x;

  float t16[16];
#pragma unroll
  for (int j = 0; j < 16; ++j) t16[j] = 0.0f;

#pragma unroll
  for (int dd = 0; dd < 4; ++dd) {
    int d = tid + dd * 256;
    float xv = bf2f(xr[d]);
    const float4* wrow = (const float4*)(Wgk1 + (size_t)d * 16);
#pragma unroll
    for (int q = 0; q < 4; ++q) {
      float4 wq = wrow[q];
      t16[q * 4 + 0] += xv * wq.x;
      t16[q * 4 + 1] += xv * wq.y;
      t16[q * 4 + 2] += xv * wq.z;
      t16[q * 4 + 3] += xv * wq.w;
    }
  }
#pragma unroll
  for (int j = 0; j < 16; ++j) {
    float s = t16[j];
#pragma unroll
    for (int o = 32; o > 0; o >>= 1) s += __shfl_down(s, o);
    t16[j] = s;
  }
  __shared__ float tmp[4][16];
  __shared__ float tf[16];
  int wid = tid >> 6;
  if ((tid & 63) == 0) {
#pragma unroll
    for (int j = 0; j < 16; ++j) tmp[wid][j] = t16[j];
  }
  __syncthreads();
  if (tid < 16) tf[tid] = tmp[0][tid] + tmp[1][tid] + tmp[2][tid] + tmp[3][tid];
  __syncthreads();

  float tl[16];
#pragma unroll
  for (int j = 0; j < 16; ++j) tl[j] = tf[j];

#pragma unroll
  for (int jj = 0; jj < 4; ++jj) {
    int n = tid * 4 + jj;
    float z = bgk2[n];
#pragma unroll
    for (int j = 0; j < 16; ++j) z += tl[j] * Wgk2[j * 1024 + n];
    float ls = fminf(z, 0.0f) - log1pf(expf(-fabsf(z)));
    gk[(size_t)row * 1024 + n] = f2bf(ls * (1.0f / 16.0f));
  }
}

// ---------------------------------------------------------------------------
// gate_chunk: per (b,h,chunk) block, 256 thr (one dk col each), bf16 in-place:
// q <- q*exp(cum)*scale; k <- k*exp(-cum); ebC = exp(cum_end) out (f32).
// ---------------------------------------------------------------------------
__global__ __launch_bounds__(256) void gate_chunk(const unsigned short* __restrict__ gk,
                                                  unsigned short* __restrict__ q,
                                                  unsigned short* __restrict__ k,
                                                  float* __restrict__ ebC) {
  int bid = blockIdx.x;
  int c = bid & 31;
  int h = (bid >> 5) & 3;
  int b = bid >> 7;
  int tid = threadIdx.x;
  size_t base = ((size_t)b * TT + c * CHK) * 1024 + h * 256 + tid;

  const float scale = 0.0625f;
  float cum = 0.0f;
  for (int t = 0; t < CHK; ++t) {
    size_t a = base + (size_t)t * 1024;
    cum += bf2f(gk[a]);
    q[a] = f2bf(bf2f(q[a]) * expf(cum) * scale);
    k[a] = f2bf(bf2f(k[a]) * expf(-cum));
  }
  ebC[((b * 4 + h) * NCHK + c) * 256 + tid] = expf(cum);
}

// ---------------------------------------------------------------------------
// intra_kernel: per (b,h,chunk): S = causal(qt @ kt^T), O_intra = S@V -> o
// bf16 inputs (converted on stage), f32 math, f32 out.
// ---------------------------------------------------------------------------
__global__ __launch_bounds__(256) void intra_kernel(
    const unsigned short* __restrict__ qt, const unsigned short* __restrict__ kt,
    const unsigned short* __restrict__ v, float* __restrict__ o) {
  __shared__ float As[16][68];
  __shared__ float Bs[16][68];
  __shared__ float Ss[64][73];
  __shared__ float Vs[64][68];
  int bid = blockIdx.x;
  int c = bid & 31;
  int h = (bid >> 5) & 3;
  int b = bid >> 7;
  size_t rowbase = ((size_t)b * TT + c * CHK) * 1024 + h * 256;
  int tid = threadIdx.x;
  int tx = tid & 15, ty = tid >> 4;

  float acc[4][4] = {};
  for (int k0 = 0; k0 < 256; k0 += 16) {
    {
      int t = tid >> 2;
      int kq = (tid & 3) * 4;
      ushort4 av = *(const ushort4*)&qt[rowbase + (size_t)t * 1024 + k0 + kq];
      As[kq + 0][t] = bf2f(av.x);
      As[kq + 1][t] = bf2f(av.y);
      As[kq + 2][t] = bf2f(av.z);
      As[kq + 3][t] = bf2f(av.w);
      ushort4 bv = *(const ushort4*)&kt[rowbase + (size_t)t * 1024 + k0 + kq];
      Bs[kq + 0][t] = bf2f(bv.x);
      Bs[kq + 1][t] = bf2f(bv.y);
      Bs[kq + 2][t] = bf2f(bv.z);
      Bs[kq + 3][t] = bf2f(bv.w);
    }
    __syncthreads();
#pragma unroll
    for (int kk = 0; kk < 16; ++kk) {
      float a4[4], b4[4];
      *(float4*)a4 = *(const float4*)&As[kk][ty * 4];
      *(float4*)b4 = *(const float4*)&Bs[kk][tx * 4];
#pragma unroll
      for (int i = 0; i < 4; ++i)
#pragma unroll
        for (int j = 0; j < 4; ++j) acc[i][j] += a4[i] * b4[j];
    }
    __syncthreads();
  }
#pragma unroll
  for (int i = 0; i < 4; ++i) {
    int t = ty * 4 + i;
#pragma unroll
    for (int j = 0; j < 4; ++j) {
      int s = tx * 4 + j;
      Ss[t][s] = (s <= t) ? acc[i][j] : 0.0f;
    }
  }
  __syncthreads();

  for (int nt = 0; nt < 4; ++nt) {
#pragma unroll
    for (int i = 0; i < 4; ++i) {
      int s = (tid >> 4) + i * 16;
      int c4 = (tid & 15) * 4;
      ushort4 vv4 = *(const ushort4*)&v[rowbase + (size_t)s * 1024 + nt * 64 + c4];
      Vs[s][c4 + 0] = bf2f(vv4.x);
      Vs[s][c4 + 1] = bf2f(vv4.y);
      Vs[s][c4 + 2] = bf2f(vv4.z);
      Vs[s][c4 + 3] = bf2f(vv4.w);
    }
    __syncthreads();
    float acc2[4][4] = {};
    for (int s = 0; s < 64; ++s) {
      float a4[4], b4[4];
#pragma unroll
      for (int i = 0; i < 4; ++i) a4[i] = Ss[ty * 4 + i][s];
      *(float4*)b4 = *(const float4*)&Vs[s][tx * 4];
#pragma unroll
      for (int i = 0; i < 4; ++i)
#pragma unroll
        for (int j = 0; j < 4; ++j) acc2[i][j] += a4[i] * b4[j];
    }
#pragma unroll
    for (int i = 0; i < 4; ++i)
#pragma unroll
      for (int j = 0; j < 4; ++j)
        o[rowbase + (size_t)(ty * 4 + i) * 1024 + nt * 64 + tx * 4 + j] =
            acc2[i][j];
    __syncthreads();
  }
}

// ---------------------------------------------------------------------------
// chunk_state: grid 16bh x 16 tiles (64dk x 64dv). khat = k~*ebC on the fly.
// Running state in regs; writes start-state H_c (bf16) per chunk.
// ---------------------------------------------------------------------------
__global__ __launch_bounds__(256) void chunk_state(
    const unsigned short* __restrict__ kt, const unsigned short* __restrict__ v,
    const float* __restrict__ ebC, unsigned short* __restrict__ Hb) {
  __shared__ float Ks[16][68];
  __shared__ float Vs[16][68];
  int bid = blockIdx.x;
  int tile = bid & 15;
  int bh = bid >> 4;
  int b = bh >> 2, h = bh & 3;
  int dk0 = (tile >> 2) * 64, dv0 = (tile & 3) * 64;
  int tid = threadIdx.x;
  int tx = tid & 15, ty = tid >> 4;

  size_t base = (size_t)b * TT * 1024 + h * 256;
  int st_ = tid >> 4;        // staging row 0..15
  int sc4 = (tid & 15) * 4;  // staging col*4

  float st[4][4] = {};
  for (int c = 0; c < NCHK; ++c) {
    const float* ec = ebC + ((size_t)bh * NCHK + c) * 256;
    float4 e4 = *(const float4*)&ec[dk0 + sc4];  // khat col factors
    float acc[4][4] = {};
    for (int ks = 0; ks < 4; ++ks) {
      int t0 = c * CHK + ks * 16;
      ushort4 kv4 = *(const ushort4*)&kt[base + (size_t)(t0 + st_) * 1024 + dk0 + sc4];
      Ks[st_][sc4 + 0] = bf2f(kv4.x) * e4.x;
      Ks[st_][sc4 + 1] = bf2f(kv4.y) * e4.y;
      Ks[st_][sc4 + 2] = bf2f(kv4.z) * e4.z;
      Ks[st_][sc4 + 3] = bf2f(kv4.w) * e4.w;
      ushort4 vv4 = *(const ushort4*)&v[base + (size_t)(t0 + st_) * 1024 + dv0 + sc4];
      Vs[st_][sc4 + 0] = bf2f(vv4.x);
      Vs[st_][sc4 + 1] = bf2f(vv4.y);
      Vs[st_][sc4 + 2] = bf2f(vv4.z);
      Vs[st_][sc4 + 3] = bf2f(vv4.w);
      __syncthreads();
#pragma unroll
      for (int kk = 0; kk < 16; ++kk) {
        float a4[4], b4[4];
        *(float4*)a4 = *(const float4*)&Ks[kk][ty * 4];
        *(float4*)b4 = *(const float4*)&Vs[kk][tx * 4];
#pragma unroll
        for (int i = 0; i < 4; ++i)
#pragma unroll
          for (int j = 0; j < 4; ++j) acc[i][j] += a4[i] * b4[j];
      }
      __syncthreads();
    }
    size_t hbase = ((size_t)bh * NCHK + c) * 65536;
    const float* ep = ebC + ((size_t)bh * NCHK + c) * 256 + dk0 + ty * 4;
#pragma unroll
    for (int i = 0; i < 4; ++i) {
      float e = ep[i];
#pragma unroll
      for (int j = 0; j < 4; ++j) {
        Hb[hbase + (size_t)(dk0 + ty * 4 + i) * 256 + dv0 + tx * 4 + j] =
            f2bf(st[i][j]);
        st[i][j] = e * st[i][j] + acc[i][j];
      }
    }
  }
}

// ---------------------------------------------------------------------------
// inter_o: grid (bh,c,ntile) = 16*32*4 = 2048 blocks. o += q~_chunk @ H_c
// M=64 (t), N=64 (dv sub), K=256 (dk). q~, H bf16.
// ---------------------------------------------------------------------------
__global__ __launch_bounds__(256) void inter_o(const unsigned short* __restrict__ qt,
                                               const unsigned short* __restrict__ Hb,
                                               float* __restrict__ o) {
  __shared__ float As[16][68];
  __shared__ float Bs[16][68];
  int bid = blockIdx.x;
  int nt = bid & 3;
  int c = (bid >> 2) & 31;
  int bh = bid >> 7;
  int b = bh >> 2, h = bh & 3;
  int n0 = nt * 64;
  int tid = threadIdx.x;
  int tx = tid & 15, ty = tid >> 4;
  size_t rowbase = ((size_t)b * TT + c * CHK) * 1024 + h * 256;
  size_t hbase = ((size_t)bh * NCHK + c) * 65536;

  float acc[4][4] = {};
  for (int k0 = 0; k0 < 256; k0 += 16) {
    {
      int t = tid >> 2;
      int kq = (tid & 3) * 4;
      ushort4 av = *(const ushort4*)&qt[rowbase + (size_t)t * 1024 + k0 + kq];
      As[kq + 0][t] = bf2f(av.x);
      As[kq + 1][t] = bf2f(av.y);
      As[kq + 2][t] = bf2f(av.z);
      As[kq + 3][t] = bf2f(av.w);
      int k = tid >> 4;
      int n4 = (tid & 15) * 4;
      const unsigned short* hp = &Hb[hbase + (size_t)(k0 + k) * 256 + n0 + n4];
      Bs[k][n4 + 0] = bf2f(hp[0]);
      Bs[k][n4 + 1] = bf2f(hp[1]);
      Bs[k][n4 + 2] = bf2f(hp[2]);
      Bs[k][n4 + 3] = bf2f(hp[3]);
    }
    __syncthreads();
#pragma unroll
    for (int kk = 0; kk < 16; ++kk) {
      float a4[4], b4[4];
      *(float4*)a4 = *(const float4*)&As[kk][ty * 4];
      *(float4*)b4 = *(const float4*)&Bs[kk][tx * 4];
#pragma unroll
      for (int i = 0; i < 4; ++i)
#pragma unroll
        for (int j = 0; j < 4; ++j) acc[i][j] += a4[i] * b4[j];
    }
    __syncthreads();
  }
#pragma unroll
  for (int i = 0; i < 4; ++i)
#pragma unroll
    for (int j = 0; j < 4; ++j)
      o[rowbase + (size_t)(ty * 4 + i) * 1024 + n0 + tx * 4 + j] += acc[i][j];
}

// ---------------------------------------------------------------------------
// Gated RMSNorm: o f32, g bf16 -> og bf16
// ---------------------------------------------------------------------------
__global__ __launch_bounds__(256) void grms_kernel(const float* __restrict__ o,
                                                   const unsigned short* __restrict__ g,
                                                   const float* __restrict__ rw,
                                                   unsigned short* __restrict__ og) {
  size_t base = (size_t)blockIdx.x * 256;
  int tid = threadIdx.x;
  float ov = o[base + tid];
  float s = ov * ov;
#pragma unroll
  for (int off = 32; off > 0; off >>= 1) s += __shfl_down(s, off);
  __shared__ float red[4];
  int wid = tid >> 6;
  if ((tid & 63) == 0) red[wid] = s;
  __syncthreads();
  float ms = (red[0] + red[1] + red[2] + red[3]) * (1.0f / 256.0f);
  float gv = bf2f(g[base + tid]);
  float sw = gv / (1.0f + expf(-gv));
  og[base + tid] = f2bf(ov * rsqrtf(ms + 1e-5f) * rw[tid] * sw);
}

// ---------------------------------------------------------------------------
extern "C" void kernel_launch(void* const* d_in, const int* in_sizes, int n_in,
                              void* d_out, int out_size, void* d_ws,
                              size_t ws_size, hipStream_t stream) {
  const float* x = (const float*)d_in[0];
  const float* ln1_w = (const float*)d_in[1];
  const float* ln1_b = (const float*)d_in[2];
  const float* Wq = (const float*)d_in[3];
  const float* Wk = (const float*)d_in[4];
  const float* Wv = (const float*)d_in[5];
  const float* Wg = (const float*)d_in[6];
  const float* Wgk1 = (const float*)d_in[7];
  const float* Wgk2 = (const float*)d_in[8];
  const float* bgk2 = (const float*)d_in[9];
  const float* rms_w = (const float*)d_in[10];
  const float* Wo = (const float*)d_in[11];
  const float* ln2_w = (const float*)d_in[12];
  const float* ln2_b = (const float*)d_in[13];
  const float* W1 = (const float*)d_in[14];
  const float* b1 = (const float*)d_in[15];
  const float* W2 = (const float*)d_in[16];
  const float* b2 = (const float*)d_in[17];
  float* out = (float*)d_out;

  const size_t S = (size_t)RR * DD;  // 8388608 elements
  // Workspace layout (bytes): 6*16.78 + 33.55 + 67.11 + 0.52 + 23.07 = 224.9MB
  unsigned short* actb = (unsigned short*)d_ws;  // xn / og / xn2 (bf16)
  unsigned short* qb = actb + S;                 // q -> q~ (bf16)
  unsigned short* kb = qb + S;                   // k -> k~ (bf16)
  unsigned short* vb = kb + S;                   // v (bf16)
  unsigned short* gb = vb + S;                   // g (bf16)
  unsigned short* gkb = gb + S;                  // gk log-gate (bf16)
  float* ofs = (float*)(gkb + S);                // o (f32, S)
  unsigned short* Hb = (unsigned short*)(ofs + S);  // chunk states, 4S bf16
  float* ebC = (float*)(Hb + 4 * S);             // 131072 f32
  unsigned short* Wqt = (unsigned short*)(ebC + 131072);
  unsigned short* Wkt = Wqt + 1048576;
  unsigned short* Wvt = Wkt + 1048576;
  unsigned short* Wgt = Wvt + 1048576;
  unsigned short* Wot = Wgt + 1048576;
  unsigned short* W1t = Wot + 1048576;
  unsigned short* W2t = W1t + 3145728;
  // overlays (dead-region reuse):
  float* x1 = (float*)kb;        // f32 S over kb+vb (dead after chunk_state)
  unsigned short* hb = Hb;       // MLP hidden 3S bf16 over Hb (dead after inter_o)

  dim3 blk(256);

  // 0. weight transposes (f32 [K,N] -> bf16 [N,K])
  transpose_cast<<<dim3(32, 32), blk, 0, stream>>>(Wq, Wqt, 1024, 1024);
  transpose_cast<<<dim3(32, 32), blk, 0, stream>>>(Wk, Wkt, 1024, 1024);
  transpose_cast<<<dim3(32, 32), blk, 0, stream>>>(Wv, Wvt, 1024, 1024);
  transpose_cast<<<dim3(32, 32), blk, 0, stream>>>(Wg, Wgt, 1024, 1024);
  transpose_cast<<<dim3(32, 32), blk, 0, stream>>>(Wo, Wot, 1024, 1024);
  transpose_cast<<<dim3(96, 32), blk, 0, stream>>>(W1, W1t, 1024, 3072);
  transpose_cast<<<dim3(32, 96), blk, 0, stream>>>(W2, W2t, 3072, 1024);

  // 1. xn = LN(x) -> bf16
  ln_kernel<<<RR, blk, 0, stream>>>(x, ln1_w, ln1_b, actb);

  // 2. projections (bf16 MFMA), bf16 outputs
  dim3 g1024(1024 / 128, RR / 128);
  gemm_bf16<0, 1><<<g1024, blk, 0, stream>>>(actb, Wqt, nullptr, nullptr, qb, RR, 1024, 1024);
  gemm_bf16<0, 1><<<g1024, blk, 0, stream>>>(actb, Wkt, nullptr, nullptr, kb, RR, 1024, 1024);
  gemm_bf16<0, 1><<<g1024, blk, 0, stream>>>(actb, Wvt, nullptr, nullptr, vb, RR, 1024, 1024);
  gemm_bf16<0, 1><<<g1024, blk, 0, stream>>>(actb, Wgt, nullptr, nullptr, gb, RR, 1024, 1024);

  // 3. gk (log) -> gkb
  gk_kernel<<<RR, blk, 0, stream>>>(actb, Wgk1, Wgk2, bgk2, gkb);

  // 4. chunked gate transforms (in-place q,k), ebC out
  gate_chunk<<<BB * HH * NCHK, blk, 0, stream>>>(gkb, qb, kb, ebC);

  // 5. intra-chunk attention -> ofs
  intra_kernel<<<BB * HH * NCHK, blk, 0, stream>>>(qb, kb, vb, ofs);

  // 6a. chunk states (bf16 H_c) from k~ (khat on the fly), v
  chunk_state<<<16 * 16, blk, 0, stream>>>(kb, vb, ebC, Hb);

  // 6b. inter contribution: o += q~ @ H_c
  inter_o<<<16 * NCHK * 4, blk, 0, stream>>>(qb, Hb, ofs);

  // 7. og = gated rmsnorm -> actb (xn dead)
  grms_kernel<<<RR * HH, blk, 0, stream>>>(ofs, gb, rms_w, actb);

  // 8. x1 = x + og @ Wo -> x1 (over dead kb/vb)
  gemm_bf16<3, 0><<<g1024, blk, 0, stream>>>(actb, Wot, nullptr, x, x1, RR, 1024, 1024);

  // 9. xn2 = LN(x1) -> actb (og dead)
  ln_kernel<<<RR, blk, 0, stream>>>(x1, ln2_w, ln2_b, actb);

  // 10. h = (leaky_relu(xn2@W1+b1))^2 -> hb (bf16, over dead Hb)
  dim3 g3072(3072 / 128, RR / 128);
  gemm_bf16<2, 1><<<g3072, blk, 0, stream>>>(actb, W1t, b1, nullptr, hb, RR, 3072, 1024);

  // 11. out = x1 + h @ W2 + b2
  gemm_bf16<4, 0><<<g1024, blk, 0, stream>>>(hb, W2t, b2, x1, out, RR, 1024, 3072);
}

// Round 5
// 581.495 us; speedup vs baseline: 8.2501x; 1.1992x over previous
//
#include <hip/hip_runtime.h>
#include <math.h>

// Problem constants
#define BB 4
#define TT 2048
#define DD 1024
#define HH 4
#define DK 256
#define DV 256
#define RR 8192
#define CHK 64
#define NCHK 32

typedef __bf16 bf16x8 __attribute__((ext_vector_type(8)));
typedef float f32x4 __attribute__((ext_vector_type(4)));

static __device__ inline unsigned short f2bf(float f) {
  unsigned int u = __float_as_uint(f);
  unsigned int r = (u + 0x7fffu + ((u >> 16) & 1u)) >> 16;
  return (unsigned short)r;
}
static __device__ inline float bf2f(unsigned short h) {
  return __uint_as_float(((unsigned int)h) << 16);
}

// async global->LDS, 16B per lane; dest = wave-uniform base + lane*16
static __device__ __forceinline__ void gload16(const unsigned short* g,
                                               unsigned short* l) {
  __builtin_amdgcn_global_load_lds(
      (const __attribute__((address_space(1))) void*)g,
      (__attribute__((address_space(3))) void*)l, 16, 0, 0);
}

// ---------------------------------------------------------------------------
// LayerNorm: one block (256 thr) per row of D=1024. f32 in -> bf16 out.
// ---------------------------------------------------------------------------
__global__ __launch_bounds__(256) void ln_kernel(const float* __restrict__ x,
                                                 const float* __restrict__ w,
                                                 const float* __restrict__ b,
                                                 unsigned short* __restrict__ yb) {
  int row = blockIdx.x;
  const float* xr = x + (size_t)row * DD;
  unsigned short* ybr = yb + (size_t)row * DD;
  int tid = threadIdx.x;

  float4 v = ((const float4*)xr)[tid];
  float s = v.x + v.y + v.z + v.w;
  float ss = v.x * v.x + v.y * v.y + v.z * v.z + v.w * v.w;
#pragma unroll
  for (int o = 32; o > 0; o >>= 1) {
    s += __shfl_down(s, o);
    ss += __shfl_down(ss, o);
  }
  __shared__ float ls[4], lss[4];
  int wid = tid >> 6;
  if ((tid & 63) == 0) { ls[wid] = s; lss[wid] = ss; }
  __syncthreads();
  float sum = ls[0] + ls[1] + ls[2] + ls[3];
  float sumsq = lss[0] + lss[1] + lss[2] + lss[3];
  float mu = sum * (1.0f / DD);
  float var = sumsq * (1.0f / DD) - mu * mu;
  float rs = rsqrtf(var + 1e-5f);

  float4 wv = ((const float4*)w)[tid];
  float4 bv = ((const float4*)b)[tid];
  ushort4 ob;
  ob.x = f2bf((v.x - mu) * rs * wv.x + bv.x);
  ob.y = f2bf((v.y - mu) * rs * wv.y + bv.y);
  ob.z = f2bf((v.z - mu) * rs * wv.z + bv.z);
  ob.w = f2bf((v.w - mu) * rs * wv.w + bv.w);
  ((ushort4*)ybr)[tid] = ob;
}

// ---------------------------------------------------------------------------
// Weight transpose + cast: W [K,N] f32 -> Wt [N,K] bf16
// ---------------------------------------------------------------------------
__global__ __launch_bounds__(256) void transpose_cast(const float* __restrict__ W,
                                                      unsigned short* __restrict__ Wt,
                                                      int K, int N) {
  __shared__ float t[32][33];
  int k0 = blockIdx.y * 32, n0 = blockIdx.x * 32;
  int tid = threadIdx.x;
  int tx = tid & 31, ty = tid >> 5;  // ty 0..7
#pragma unroll
  for (int i = 0; i < 4; ++i)
    t[ty + i * 8][tx] = W[(size_t)(k0 + ty + i * 8) * N + n0 + tx];
  __syncthreads();
#pragma unroll
  for (int i = 0; i < 4; ++i)
    Wt[(size_t)(n0 + ty + i * 8) * K + k0 + tx] = f2bf(t[tx][ty + i * 8]);
}

// ---------------------------------------------------------------------------
// bf16 MFMA GEMM: C[M,N] = A[M,K] @ Bt[N,K]^T  (+epilogue)
// 128x128 tile, BK=64, global_load_lds staging, XOR-swizzled LDS
// (linear dest + inverse-swz source + swz read; granule^=(row&7)).
// EPI: 0 none, 2 +bias,(leaky)^2, 3 +res, 4 +bias+res.  OUTBF: bf16 vs f32.
// ---------------------------------------------------------------------------
template <int EPI, int OUTBF>
__global__ __launch_bounds__(256) void gemm_bf16(
    const unsigned short* __restrict__ A,   // [M,K] bf16
    const unsigned short* __restrict__ Bt,  // [N,K] bf16
    const float* __restrict__ bias, const float* __restrict__ Res,
    void* __restrict__ Cv, int M, int N, int K) {
  __shared__ unsigned short As[128 * 64];  // [row][64 bf16] = 128B rows
  __shared__ unsigned short Bs[128 * 64];
  int tid = threadIdx.x;
  int m0 = blockIdx.y * 128, n0 = blockIdx.x * 128;
  int lane = tid & 63;
  int w64 = tid & 192;  // wave * 64
  int wid = tid >> 6;
  int wm = (wid >> 1) * 64, wn = (wid & 1) * 64;
  int fr = lane & 15, fq = lane >> 4;

  f32x4 acc[4][4] = {};

  for (int k0 = 0; k0 < K; k0 += 64) {
    __syncthreads();
#pragma unroll
    for (int j = 0; j < 4; ++j) {
      int gl = j * 256 + tid;           // granule 0..1023
      int row = gl >> 3;
      int gs = (gl & 7) ^ (row & 7);    // inverse-swizzled source granule
      gload16(&A[(size_t)(m0 + row) * K + k0 + gs * 8],
              &As[(size_t)(j * 256 + w64) * 8]);
      gload16(&Bt[(size_t)(n0 + row) * K + k0 + gs * 8],
              &Bs[(size_t)(j * 256 + w64) * 8]);
    }
    __syncthreads();  // drains vmcnt -> staged data visible

#pragma unroll
    for (int ph = 0; ph < 2; ++ph) {
      bf16x8 af[4], bv[4];
#pragma unroll
      for (int i = 0; i < 4; ++i) {
        int ra = wm + i * 16 + fr;
        af[i] = *(const bf16x8*)&As[ra * 64 + (((ph * 4 + fq) ^ (ra & 7)) * 8)];
        int rb = wn + i * 16 + fr;
        bv[i] = *(const bf16x8*)&Bs[rb * 64 + (((ph * 4 + fq) ^ (rb & 7)) * 8)];
      }
#pragma unroll
      for (int i = 0; i < 4; ++i)
#pragma unroll
        for (int jj = 0; jj < 4; ++jj)
          acc[i][jj] = __builtin_amdgcn_mfma_f32_16x16x32_bf16(af[i], bv[jj],
                                                               acc[i][jj], 0, 0, 0);
    }
  }

  // epilogue: C/D layout col=lane&15, row=(lane>>4)*4+r  [verified m89/m91]
  int col = lane & 15;
  int rbase = (lane >> 4) * 4;
#pragma unroll
  for (int i = 0; i < 4; ++i) {
#pragma unroll
    for (int j = 0; j < 4; ++j) {
      int n = n0 + wn + j * 16 + col;
      float bvv = (EPI == 2 || EPI == 4) ? bias[n] : 0.0f;
#pragma unroll
      for (int r = 0; r < 4; ++r) {
        int m = m0 + wm + i * 16 + rbase + r;
        float vv = acc[i][j][r] + bvv;
        if (EPI == 2) {
          float t = vv > 0.0f ? vv : 0.01f * vv;
          vv = t * t;
        }
        if (EPI == 3 || EPI == 4) vv += Res[(size_t)m * N + n];
        if (OUTBF)
          ((unsigned short*)Cv)[(size_t)m * N + n] = f2bf(vv);
        else
          ((float*)Cv)[(size_t)m * N + n] = vv;
      }
    }
  }
}

// ---------------------------------------------------------------------------
// Low-rank forget gate -> LOG gate gk = log_sigmoid(z)/16 (bf16 in/out)
// ---------------------------------------------------------------------------
__global__ __launch_bounds__(256) void gk_kernel(const unsigned short* __restrict__ xn,
                                                 const float* __restrict__ Wgk1,
                                                 const float* __restrict__ Wgk2,
                                                 const float* __restrict__ bgk2,
                                                 unsigned short* __restrict__ gk) {
  int row = blockIdx.x;
  const unsigned short* xr = xn + (size_t)row * DD;
  int tid = threadIdx.x;

  float t16[16];
#pragma unroll
  for (int j = 0; j < 16; ++j) t16[j] = 0.0f;

#pragma unroll
  for (int dd = 0; dd < 4; ++dd) {
    int d = tid + dd * 256;
    float xv = bf2f(xr[d]);
    const float4* wrow = (const float4*)(Wgk1 + (size_t)d * 16);
#pragma unroll
    for (int q = 0; q < 4; ++q) {
      float4 wq = wrow[q];
      t16[q * 4 + 0] += xv * wq.x;
      t16[q * 4 + 1] += xv * wq.y;
      t16[q * 4 + 2] += xv * wq.z;
      t16[q * 4 + 3] += xv * wq.w;
    }
  }
#pragma unroll
  for (int j = 0; j < 16; ++j) {
    float s = t16[j];
#pragma unroll
    for (int o = 32; o > 0; o >>= 1) s += __shfl_down(s, o);
    t16[j] = s;
  }
  __shared__ float tmp[4][16];
  __shared__ float tf[16];
  int wid = tid >> 6;
  if ((tid & 63) == 0) {
#pragma unroll
    for (int j = 0; j < 16; ++j) tmp[wid][j] = t16[j];
  }
  __syncthreads();
  if (tid < 16) tf[tid] = tmp[0][tid] + tmp[1][tid] + tmp[2][tid] + tmp[3][tid];
  __syncthreads();

  float tl[16];
#pragma unroll
  for (int j = 0; j < 16; ++j) tl[j] = tf[j];

#pragma unroll
  for (int jj = 0; jj < 4; ++jj) {
    int n = tid * 4 + jj;
    float z = bgk2[n];
#pragma unroll
    for (int j = 0; j < 16; ++j) z += tl[j] * Wgk2[j * 1024 + n];
    float ls = fminf(z, 0.0f) - log1pf(expf(-fabsf(z)));
    gk[(size_t)row * 1024 + n] = f2bf(ls * (1.0f / 16.0f));
  }
}

// ---------------------------------------------------------------------------
// gate_chunk: per (b,h,chunk) block, 256 thr (one dk col each), bf16 in-place:
// q <- q*exp(cum)*scale; k <- k*exp(-cum); ebC = exp(cum_end) out (f32).
// ---------------------------------------------------------------------------
__global__ __launch_bounds__(256) void gate_chunk(const unsigned short* __restrict__ gk,
                                                  unsigned short* __restrict__ q,
                                                  unsigned short* __restrict__ k,
                                                  float* __restrict__ ebC) {
  int bid = blockIdx.x;
  int c = bid & 31;
  int h = (bid >> 5) & 3;
  int b = bid >> 7;
  int tid = threadIdx.x;
  size_t base = ((size_t)b * TT + c * CHK) * 1024 + h * 256 + tid;

  const float scale = 0.0625f;
  float cum = 0.0f;
  for (int t = 0; t < CHK; ++t) {
    size_t a = base + (size_t)t * 1024;
    cum += bf2f(gk[a]);
    q[a] = f2bf(bf2f(q[a]) * expf(cum) * scale);
    k[a] = f2bf(bf2f(k[a]) * expf(-cum));
  }
  ebC[((b * 4 + h) * NCHK + c) * 256 + tid] = expf(cum);
}

// ---------------------------------------------------------------------------
// trans_kernel: [B*T, H*256] slice -> T-major [bh][256][2048]; WITHE folds ebC
// (khat = k~ * exp(bC)).  grid = 16bh x 32t-tiles(=chunks) x 4dk-tiles.
// ---------------------------------------------------------------------------
template <int WITHE>
__global__ __launch_bounds__(256) void trans_kernel(const unsigned short* __restrict__ in,
                                                    const float* __restrict__ ebC,
                                                    unsigned short* __restrict__ outT) {
  __shared__ unsigned short T[64][68];
  int bid = blockIdx.x;
  int dkt = bid & 3;
  int ct = (bid >> 2) & 31;
  int bh = bid >> 7;
  int b = bh >> 2, h = bh & 3;
  int tid = threadIdx.x;
  int r = tid >> 4;            // 0..15
  int c4 = (tid & 15) * 4;
  size_t srcbase = ((size_t)b * TT + ct * 64) * 1024 + h * 256 + dkt * 64;
#pragma unroll
  for (int i = 0; i < 4; ++i)
    *(ushort4*)&T[r + i * 16][c4] =
        *(const ushort4*)&in[srcbase + (size_t)(r + i * 16) * 1024 + c4];
  __syncthreads();
  size_t outbase = (size_t)bh * 524288 + (size_t)(dkt * 64) * 2048 + ct * 64;
  const float* ep = ebC + ((size_t)bh * 32 + ct) * 256 + dkt * 64;
#pragma unroll
  for (int i = 0; i < 4; ++i) {
    int dkl = r + i * 16;
    float e = WITHE ? ep[dkl] : 1.0f;
    ushort4 o;
    o.x = f2bf(bf2f(T[c4 + 0][dkl]) * e);
    o.y = f2bf(bf2f(T[c4 + 1][dkl]) * e);
    o.z = f2bf(bf2f(T[c4 + 2][dkl]) * e);
    o.w = f2bf(bf2f(T[c4 + 3][dkl]) * e);
    *(ushort4*)&outT[outbase + (size_t)dkl * 2048 + c4] = o;
  }
}

// ---------------------------------------------------------------------------
// u_gemm: per (bh,c,tile): U_c[128dk x 128dv] = khatT_slice @ vT_slice^T, K=64.
// Same staging/swizzle as gemm_bf16; single K-step. Writes bf16 U.
// ---------------------------------------------------------------------------
__global__ __launch_bounds__(256) void u_gemm(const unsigned short* __restrict__ khatT,
                                              const unsigned short* __restrict__ vT,
                                              unsigned short* __restrict__ U) {
  __shared__ unsigned short As[128 * 64];
  __shared__ unsigned short Bs[128 * 64];
  int tid = threadIdx.x;
  int bid = blockIdx.x;
  int tile = bid & 3;
  int bhc = bid >> 2;  // bh*32 + c
  int bh = bhc >> 5, c = bhc & 31;
  int m0 = (tile >> 1) * 128, n0 = (tile & 1) * 128;
  const unsigned short* Ab = khatT + (size_t)bh * 524288 + c * 64;
  const unsigned short* Bb = vT + (size_t)bh * 524288 + c * 64;
  unsigned short* Cb = U + (size_t)bhc * 65536;

  int lane = tid & 63;
  int w64 = tid & 192;
  int wid = tid >> 6;
  int wm = (wid >> 1) * 64, wn = (wid & 1) * 64;
  int fr = lane & 15, fq = lane >> 4;

  f32x4 acc[4][4] = {};

#pragma unroll
  for (int j = 0; j < 4; ++j) {
    int gl = j * 256 + tid;
    int row = gl >> 3;
    int gs = (gl & 7) ^ (row & 7);
    gload16(&Ab[(size_t)(m0 + row) * 2048 + gs * 8],
            &As[(size_t)(j * 256 + w64) * 8]);
    gload16(&Bb[(size_t)(n0 + row) * 2048 + gs * 8],
            &Bs[(size_t)(j * 256 + w64) * 8]);
  }
  __syncthreads();

#pragma unroll
  for (int ph = 0; ph < 2; ++ph) {
    bf16x8 af[4], bv[4];
#pragma unroll
    for (int i = 0; i < 4; ++i) {
      int ra = wm + i * 16 + fr;
      af[i] = *(const bf16x8*)&As[ra * 64 + (((ph * 4 + fq) ^ (ra & 7)) * 8)];
      int rb = wn + i * 16 + fr;
      bv[i] = *(const bf16x8*)&Bs[rb * 64 + (((ph * 4 + fq) ^ (rb & 7)) * 8)];
    }
#pragma unroll
    for (int i = 0; i < 4; ++i)
#pragma unroll
      for (int jj = 0; jj < 4; ++jj)
        acc[i][jj] = __builtin_amdgcn_mfma_f32_16x16x32_bf16(af[i], bv[jj],
                                                             acc[i][jj], 0, 0, 0);
  }

  int col = lane & 15;
  int rbase = (lane >> 4) * 4;
#pragma unroll
  for (int i = 0; i < 4; ++i)
#pragma unroll
    for (int j = 0; j < 4; ++j) {
      int n = n0 + wn + j * 16 + col;
#pragma unroll
      for (int r = 0; r < 4; ++r) {
        int m = m0 + wm + i * 16 + rbase + r;
        Cb[(size_t)m * 256 + n] = f2bf(acc[i][j][r]);
      }
    }
}

// ---------------------------------------------------------------------------
// hscan: in-place U -> H (chunk-start states). grid = 16bh x 256dk; thread=dv.
// h=0; for c: u=U_c; U_c <- h; h = e_c*h + u.
// ---------------------------------------------------------------------------
__global__ __launch_bounds__(256) void hscan(unsigned short* __restrict__ UH,
                                             const float* __restrict__ ebC) {
  int bid = blockIdx.x;
  int bh = bid >> 8, dk = bid & 255;
  int tid = threadIdx.x;
  size_t base = ((size_t)bh * NCHK) * 65536 + (size_t)dk * 256 + tid;
  const float* ep = ebC + (size_t)bh * NCHK * 256 + dk;
  float h = 0.0f;
  for (int c = 0; c < NCHK; ++c) {
    size_t a = base + (size_t)c * 65536;
    float u = bf2f(UH[a]);
    UH[a] = f2bf(h);
    h = ep[c * 256] * h + u;
  }
}

// ---------------------------------------------------------------------------
// intra_kernel: per (b,h,chunk): S = causal(qt @ kt^T), O_intra = S@V -> o
// ---------------------------------------------------------------------------
__global__ __launch_bounds__(256) void intra_kernel(
    const unsigned short* __restrict__ qt, const unsigned short* __restrict__ kt,
    const unsigned short* __restrict__ v, float* __restrict__ o) {
  __shared__ float As[16][68];
  __shared__ float Bs[16][68];
  __shared__ float Ss[64][73];
  __shared__ float Vs[64][68];
  int bid = blockIdx.x;
  int c = bid & 31;
  int h = (bid >> 5) & 3;
  int b = bid >> 7;
  size_t rowbase = ((size_t)b * TT + c * CHK) * 1024 + h * 256;
  int tid = threadIdx.x;
  int tx = tid & 15, ty = tid >> 4;

  float acc[4][4] = {};
  for (int k0 = 0; k0 < 256; k0 += 16) {
    {
      int t = tid >> 2;
      int kq = (tid & 3) * 4;
      ushort4 av = *(const ushort4*)&qt[rowbase + (size_t)t * 1024 + k0 + kq];
      As[kq + 0][t] = bf2f(av.x);
      As[kq + 1][t] = bf2f(av.y);
      As[kq + 2][t] = bf2f(av.z);
      As[kq + 3][t] = bf2f(av.w);
      ushort4 bv = *(const ushort4*)&kt[rowbase + (size_t)t * 1024 + k0 + kq];
      Bs[kq + 0][t] = bf2f(bv.x);
      Bs[kq + 1][t] = bf2f(bv.y);
      Bs[kq + 2][t] = bf2f(bv.z);
      Bs[kq + 3][t] = bf2f(bv.w);
    }
    __syncthreads();
#pragma unroll
    for (int kk = 0; kk < 16; ++kk) {
      float a4[4], b4[4];
      *(float4*)a4 = *(const float4*)&As[kk][ty * 4];
      *(float4*)b4 = *(const float4*)&Bs[kk][tx * 4];
#pragma unroll
      for (int i = 0; i < 4; ++i)
#pragma unroll
        for (int j = 0; j < 4; ++j) acc[i][j] += a4[i] * b4[j];
    }
    __syncthreads();
  }
#pragma unroll
  for (int i = 0; i < 4; ++i) {
    int t = ty * 4 + i;
#pragma unroll
    for (int j = 0; j < 4; ++j) {
      int s = tx * 4 + j;
      Ss[t][s] = (s <= t) ? acc[i][j] : 0.0f;
    }
  }
  __syncthreads();

  for (int nt = 0; nt < 4; ++nt) {
#pragma unroll
    for (int i = 0; i < 4; ++i) {
      int s = (tid >> 4) + i * 16;
      int c4 = (tid & 15) * 4;
      ushort4 vv4 = *(const ushort4*)&v[rowbase + (size_t)s * 1024 + nt * 64 + c4];
      Vs[s][c4 + 0] = bf2f(vv4.x);
      Vs[s][c4 + 1] = bf2f(vv4.y);
      Vs[s][c4 + 2] = bf2f(vv4.z);
      Vs[s][c4 + 3] = bf2f(vv4.w);
    }
    __syncthreads();
    float acc2[4][4] = {};
    for (int s = 0; s < 64; ++s) {
      float a4[4], b4[4];
#pragma unroll
      for (int i = 0; i < 4; ++i) a4[i] = Ss[ty * 4 + i][s];
      *(float4*)b4 = *(const float4*)&Vs[s][tx * 4];
#pragma unroll
      for (int i = 0; i < 4; ++i)
#pragma unroll
        for (int j = 0; j < 4; ++j) acc2[i][j] += a4[i] * b4[j];
    }
#pragma unroll
    for (int i = 0; i < 4; ++i)
#pragma unroll
      for (int j = 0; j < 4; ++j)
        o[rowbase + (size_t)(ty * 4 + i) * 1024 + nt * 64 + tx * 4 + j] =
            acc2[i][j];
    __syncthreads();
  }
}

// ---------------------------------------------------------------------------
// inter_o: grid (bh,c,ntile) = 2048 blocks. o += q~_chunk @ H_c
// ---------------------------------------------------------------------------
__global__ __launch_bounds__(256) void inter_o(const unsigned short* __restrict__ qt,
                                               const unsigned short* __restrict__ Hb,
                                               float* __restrict__ o) {
  __shared__ float As[16][68];
  __shared__ float Bs[16][68];
  int bid = blockIdx.x;
  int nt = bid & 3;
  int c = (bid >> 2) & 31;
  int bh = bid >> 7;
  int b = bh >> 2, h = bh & 3;
  int n0 = nt * 64;
  int tid = threadIdx.x;
  int tx = tid & 15, ty = tid >> 4;
  size_t rowbase = ((size_t)b * TT + c * CHK) * 1024 + h * 256;
  size_t hbase = ((size_t)bh * NCHK + c) * 65536;

  float acc[4][4] = {};
  for (int k0 = 0; k0 < 256; k0 += 16) {
    {
      int t = tid >> 2;
      int kq = (tid & 3) * 4;
      ushort4 av = *(const ushort4*)&qt[rowbase + (size_t)t * 1024 + k0 + kq];
      As[kq + 0][t] = bf2f(av.x);
      As[kq + 1][t] = bf2f(av.y);
      As[kq + 2][t] = bf2f(av.z);
      As[kq + 3][t] = bf2f(av.w);
      int k = tid >> 4;
      int n4 = (tid & 15) * 4;
      const unsigned short* hp = &Hb[hbase + (size_t)(k0 + k) * 256 + n0 + n4];
      Bs[k][n4 + 0] = bf2f(hp[0]);
      Bs[k][n4 + 1] = bf2f(hp[1]);
      Bs[k][n4 + 2] = bf2f(hp[2]);
      Bs[k][n4 + 3] = bf2f(hp[3]);
    }
    __syncthreads();
#pragma unroll
    for (int kk = 0; kk < 16; ++kk) {
      float a4[4], b4[4];
      *(float4*)a4 = *(const float4*)&As[kk][ty * 4];
      *(float4*)b4 = *(const float4*)&Bs[kk][tx * 4];
#pragma unroll
      for (int i = 0; i < 4; ++i)
#pragma unroll
        for (int j = 0; j < 4; ++j) acc[i][j] += a4[i] * b4[j];
    }
    __syncthreads();
  }
#pragma unroll
  for (int i = 0; i < 4; ++i)
#pragma unroll
    for (int j = 0; j < 4; ++j)
      o[rowbase + (size_t)(ty * 4 + i) * 1024 + n0 + tx * 4 + j] += acc[i][j];
}

// ---------------------------------------------------------------------------
// Gated RMSNorm: o f32, g bf16 -> og bf16
// ---------------------------------------------------------------------------
__global__ __launch_bounds__(256) void grms_kernel(const float* __restrict__ o,
                                                   const unsigned short* __restrict__ g,
                                                   const float* __restrict__ rw,
                                                   unsigned short* __restrict__ og) {
  size_t base = (size_t)blockIdx.x * 256;
  int tid = threadIdx.x;
  float ov = o[base + tid];
  float s = ov * ov;
#pragma unroll
  for (int off = 32; off > 0; off >>= 1) s += __shfl_down(s, off);
  __shared__ float red[4];
  int wid = tid >> 6;
  if ((tid & 63) == 0) red[wid] = s;
  __syncthreads();
  float ms = (red[0] + red[1] + red[2] + red[3]) * (1.0f / 256.0f);
  float gv = bf2f(g[base + tid]);
  float sw = gv / (1.0f + expf(-gv));
  og[base + tid] = f2bf(ov * rsqrtf(ms + 1e-5f) * rw[tid] * sw);
}

// ---------------------------------------------------------------------------
extern "C" void kernel_launch(void* const* d_in, const int* in_sizes, int n_in,
                              void* d_out, int out_size, void* d_ws,
                              size_t ws_size, hipStream_t stream) {
  const float* x = (const float*)d_in[0];
  const float* ln1_w = (const float*)d_in[1];
  const float* ln1_b = (const float*)d_in[2];
  const float* Wq = (const float*)d_in[3];
  const float* Wk = (const float*)d_in[4];
  const float* Wv = (const float*)d_in[5];
  const float* Wg = (const float*)d_in[6];
  const float* Wgk1 = (const float*)d_in[7];
  const float* Wgk2 = (const float*)d_in[8];
  const float* bgk2 = (const float*)d_in[9];
  const float* rms_w = (const float*)d_in[10];
  const float* Wo = (const float*)d_in[11];
  const float* ln2_w = (const float*)d_in[12];
  const float* ln2_b = (const float*)d_in[13];
  const float* W1 = (const float*)d_in[14];
  const float* b1 = (const float*)d_in[15];
  const float* W2 = (const float*)d_in[16];
  const float* b2 = (const float*)d_in[17];
  float* out = (float*)d_out;

  const size_t S = (size_t)RR * DD;  // 8388608 elements
  unsigned short* actb = (unsigned short*)d_ws;  // xn -> vT -> og/xn2
  unsigned short* qb = actb + S;                 // q~
  unsigned short* kb = qb + S;                   // k~
  unsigned short* vb = kb + S;                   // v
  unsigned short* gb = vb + S;                   // g
  unsigned short* gkb = gb + S;                  // gk -> khatT
  float* ofs = (float*)(gkb + S);                // o (f32, S)
  unsigned short* UH = (unsigned short*)(ofs + S);  // U -> H, 4S bf16
  float* ebC = (float*)(UH + 4 * S);             // 131072 f32
  unsigned short* Wqt = (unsigned short*)(ebC + 131072);
  unsigned short* Wkt = Wqt + 1048576;
  unsigned short* Wvt = Wkt + 1048576;
  unsigned short* Wgt = Wvt + 1048576;
  unsigned short* Wot = Wgt + 1048576;
  unsigned short* W1t = Wot + 1048576;
  unsigned short* W2t = W1t + 3145728;
  // overlays:
  unsigned short* khatT = gkb;   // after gate_chunk, gk dead
  unsigned short* vT = actb;     // after gk_kernel, xn dead
  float* x1 = (float*)kb;        // f32 S over kb+vb (dead after intra/ktrans)
  unsigned short* hb = UH;       // MLP hidden 3S bf16 (UH dead after inter_o)

  dim3 blk(256);

  // 0. weight transposes
  transpose_cast<<<dim3(32, 32), blk, 0, stream>>>(Wq, Wqt, 1024, 1024);
  transpose_cast<<<dim3(32, 32), blk, 0, stream>>>(Wk, Wkt, 1024, 1024);
  transpose_cast<<<dim3(32, 32), blk, 0, stream>>>(Wv, Wvt, 1024, 1024);
  transpose_cast<<<dim3(32, 32), blk, 0, stream>>>(Wg, Wgt, 1024, 1024);
  transpose_cast<<<dim3(32, 32), blk, 0, stream>>>(Wo, Wot, 1024, 1024);
  transpose_cast<<<dim3(96, 32), blk, 0, stream>>>(W1, W1t, 1024, 3072);
  transpose_cast<<<dim3(32, 96), blk, 0, stream>>>(W2, W2t, 3072, 1024);

  // 1. xn = LN(x)
  ln_kernel<<<RR, blk, 0, stream>>>(x, ln1_w, ln1_b, actb);

  // 2. projections
  dim3 g1024(1024 / 128, RR / 128);
  gemm_bf16<0, 1><<<g1024, blk, 0, stream>>>(actb, Wqt, nullptr, nullptr, qb, RR, 1024, 1024);
  gemm_bf16<0, 1><<<g1024, blk, 0, stream>>>(actb, Wkt, nullptr, nullptr, kb, RR, 1024, 1024);
  gemm_bf16<0, 1><<<g1024, blk, 0, stream>>>(actb, Wvt, nullptr, nullptr, vb, RR, 1024, 1024);
  gemm_bf16<0, 1><<<g1024, blk, 0, stream>>>(actb, Wgt, nullptr, nullptr, gb, RR, 1024, 1024);

  // 3. gk -> gkb
  gk_kernel<<<RR, blk, 0, stream>>>(actb, Wgk1, Wgk2, bgk2, gkb);

  // 4. gate transforms (in-place q,k), ebC
  gate_chunk<<<BB * HH * NCHK, blk, 0, stream>>>(gkb, qb, kb, ebC);

  // 5. transposes: khatT (ebC folded) over gkb; vT over actb
  trans_kernel<1><<<16 * 32 * 4, blk, 0, stream>>>(kb, ebC, khatT);
  trans_kernel<0><<<16 * 32 * 4, blk, 0, stream>>>(vb, ebC, vT);

  // 6. U_c = khat^T v (MFMA) -> UH ; then in-place scan -> H
  u_gemm<<<16 * NCHK * 4, blk, 0, stream>>>(khatT, vT, UH);
  hscan<<<16 * 256, blk, 0, stream>>>(UH, ebC);

  // 7. intra-chunk -> ofs ; inter adds q~ @ H_c
  intra_kernel<<<BB * HH * NCHK, blk, 0, stream>>>(qb, kb, vb, ofs);
  inter_o<<<16 * NCHK * 4, blk, 0, stream>>>(qb, UH, ofs);

  // 8. og = gated rmsnorm -> actb (vT dead)
  grms_kernel<<<RR * HH, blk, 0, stream>>>(ofs, gb, rms_w, actb);

  // 9. x1 = x + og @ Wo
  gemm_bf16<3, 0><<<g1024, blk, 0, stream>>>(actb, Wot, nullptr, x, x1, RR, 1024, 1024);

  // 10. xn2 = LN(x1) -> actb
  ln_kernel<<<RR, blk, 0, stream>>>(x1, ln2_w, ln2_b, actb);

  // 11. h = (leaky_relu(xn2@W1+b1))^2 -> hb (over UH)
  dim3 g3072(3072 / 128, RR / 128);
  gemm_bf16<2, 1><<<g3072, blk, 0, stream>>>(actb, W1t, b1, nullptr, hb, RR, 3072, 1024);

  // 12. out = x1 + h @ W2 + b2
  gemm_bf16<4, 0><<<g1024, blk, 0, stream>>>(hb, W2t, b2, x1, out, RR, 1024, 3072);
}

// Round 6
// 497.631 us; speedup vs baseline: 9.6405x; 1.1685x over previous
//
#include <hip/hip_runtime.h>
#include <math.h>

// Problem constants
#define BB 4
#define TT 2048
#define DD 1024
#define HH 4
#define DK 256
#define DV 256
#define RR 8192
#define CHK 64
#define NCHK 32

typedef __bf16 bf16x8 __attribute__((ext_vector_type(8)));
typedef float f32x4 __attribute__((ext_vector_type(4)));

static __device__ inline unsigned short f2bf(float f) {
  unsigned int u = __float_as_uint(f);
  unsigned int r = (u + 0x7fffu + ((u >> 16) & 1u)) >> 16;
  return (unsigned short)r;
}
static __device__ inline float bf2f(unsigned short h) {
  return __uint_as_float(((unsigned int)h) << 16);
}

// async global->LDS, 16B per lane; dest = wave-uniform base + lane*16
static __device__ __forceinline__ void gload16(const unsigned short* g,
                                               unsigned short* l) {
  __builtin_amdgcn_global_load_lds(
      (const __attribute__((address_space(1))) void*)g,
      (__attribute__((address_space(3))) void*)l, 16, 0, 0);
}

// ---------------------------------------------------------------------------
// LayerNorm: one block (256 thr) per row of D=1024. f32 in -> bf16 out.
// ---------------------------------------------------------------------------
__global__ __launch_bounds__(256) void ln_kernel(const float* __restrict__ x,
                                                 const float* __restrict__ w,
                                                 const float* __restrict__ b,
                                                 unsigned short* __restrict__ yb) {
  int row = blockIdx.x;
  const float* xr = x + (size_t)row * DD;
  unsigned short* ybr = yb + (size_t)row * DD;
  int tid = threadIdx.x;

  float4 v = ((const float4*)xr)[tid];
  float s = v.x + v.y + v.z + v.w;
  float ss = v.x * v.x + v.y * v.y + v.z * v.z + v.w * v.w;
#pragma unroll
  for (int o = 32; o > 0; o >>= 1) {
    s += __shfl_down(s, o);
    ss += __shfl_down(ss, o);
  }
  __shared__ float ls[4], lss[4];
  int wid = tid >> 6;
  if ((tid & 63) == 0) { ls[wid] = s; lss[wid] = ss; }
  __syncthreads();
  float sum = ls[0] + ls[1] + ls[2] + ls[3];
  float sumsq = lss[0] + lss[1] + lss[2] + lss[3];
  float mu = sum * (1.0f / DD);
  float var = sumsq * (1.0f / DD) - mu * mu;
  float rs = rsqrtf(var + 1e-5f);

  float4 wv = ((const float4*)w)[tid];
  float4 bv = ((const float4*)b)[tid];
  ushort4 ob;
  ob.x = f2bf((v.x - mu) * rs * wv.x + bv.x);
  ob.y = f2bf((v.y - mu) * rs * wv.y + bv.y);
  ob.z = f2bf((v.z - mu) * rs * wv.z + bv.z);
  ob.w = f2bf((v.w - mu) * rs * wv.w + bv.w);
  ((ushort4*)ybr)[tid] = ob;
}

// ---------------------------------------------------------------------------
// Weight transpose + cast: W [K,N] f32 -> Wt [N,K] bf16
// ---------------------------------------------------------------------------
__global__ __launch_bounds__(256) void transpose_cast(const float* __restrict__ W,
                                                      unsigned short* __restrict__ Wt,
                                                      int K, int N) {
  __shared__ float t[32][33];
  int k0 = blockIdx.y * 32, n0 = blockIdx.x * 32;
  int tid = threadIdx.x;
  int tx = tid & 31, ty = tid >> 5;  // ty 0..7
#pragma unroll
  for (int i = 0; i < 4; ++i)
    t[ty + i * 8][tx] = W[(size_t)(k0 + ty + i * 8) * N + n0 + tx];
  __syncthreads();
#pragma unroll
  for (int i = 0; i < 4; ++i)
    Wt[(size_t)(n0 + ty + i * 8) * K + k0 + tx] = f2bf(t[tx][ty + i * 8]);
}

// ---------------------------------------------------------------------------
// bf16 MFMA GEMM: C[M,N] = A[M,K] @ Bt[N,K]^T  (+epilogue)
// 128x128 tile, BK=64, global_load_lds staging, XOR-swizzled LDS,
// XCD-aware block swizzle (grid size must be %8==0).
// EPI: 0 none, 2 +bias,(leaky)^2, 3 +res, 4 +bias+res.  OUTBF: bf16 vs f32.
// ---------------------------------------------------------------------------
template <int EPI, int OUTBF>
__global__ __launch_bounds__(256) void gemm_bf16(
    const unsigned short* __restrict__ A,   // [M,K] bf16
    const unsigned short* __restrict__ Bt,  // [N,K] bf16
    const float* __restrict__ bias, const float* __restrict__ Res,
    void* __restrict__ Cv, int M, int N, int K) {
  __shared__ unsigned short As[128 * 64];  // [row][64 bf16] = 128B rows
  __shared__ unsigned short Bs[128 * 64];
  int tid = threadIdx.x;
  // XCD-aware swizzle: contiguous chunk of wgs per XCD (nwg % 8 == 0)
  int nwg = gridDim.x * gridDim.y;
  int wg = blockIdx.y * gridDim.x + blockIdx.x;
  int cpx = nwg >> 3;
  wg = (wg & 7) * cpx + (wg >> 3);
  int m0 = (wg / gridDim.x) * 128, n0 = (wg % gridDim.x) * 128;
  int lane = tid & 63;
  int w64 = tid & 192;  // wave * 64
  int wid = tid >> 6;
  int wm = (wid >> 1) * 64, wn = (wid & 1) * 64;
  int fr = lane & 15, fq = lane >> 4;

  f32x4 acc[4][4] = {};

  for (int k0 = 0; k0 < K; k0 += 64) {
    __syncthreads();
#pragma unroll
    for (int j = 0; j < 4; ++j) {
      int gl = j * 256 + tid;           // granule 0..1023
      int row = gl >> 3;
      int gs = (gl & 7) ^ (row & 7);    // inverse-swizzled source granule
      gload16(&A[(size_t)(m0 + row) * K + k0 + gs * 8],
              &As[(size_t)(j * 256 + w64) * 8]);
      gload16(&Bt[(size_t)(n0 + row) * K + k0 + gs * 8],
              &Bs[(size_t)(j * 256 + w64) * 8]);
    }
    __syncthreads();  // drains vmcnt -> staged data visible

#pragma unroll
    for (int ph = 0; ph < 2; ++ph) {
      bf16x8 af[4], bv[4];
#pragma unroll
      for (int i = 0; i < 4; ++i) {
        int ra = wm + i * 16 + fr;
        af[i] = *(const bf16x8*)&As[ra * 64 + (((ph * 4 + fq) ^ (ra & 7)) * 8)];
        int rb = wn + i * 16 + fr;
        bv[i] = *(const bf16x8*)&Bs[rb * 64 + (((ph * 4 + fq) ^ (rb & 7)) * 8)];
      }
#pragma unroll
      for (int i = 0; i < 4; ++i)
#pragma unroll
        for (int jj = 0; jj < 4; ++jj)
          acc[i][jj] = __builtin_amdgcn_mfma_f32_16x16x32_bf16(af[i], bv[jj],
                                                               acc[i][jj], 0, 0, 0);
    }
  }

  // epilogue: C/D layout col=lane&15, row=(lane>>4)*4+r
  int col = lane & 15;
  int rbase = (lane >> 4) * 4;
#pragma unroll
  for (int i = 0; i < 4; ++i) {
#pragma unroll
    for (int j = 0; j < 4; ++j) {
      int n = n0 + wn + j * 16 + col;
      float bvv = (EPI == 2 || EPI == 4) ? bias[n] : 0.0f;
#pragma unroll
      for (int r = 0; r < 4; ++r) {
        int m = m0 + wm + i * 16 + rbase + r;
        float vv = acc[i][j][r] + bvv;
        if (EPI == 2) {
          float t = vv > 0.0f ? vv : 0.01f * vv;
          vv = t * t;
        }
        if (EPI == 3 || EPI == 4) vv += Res[(size_t)m * N + n];
        if (OUTBF)
          ((unsigned short*)Cv)[(size_t)m * N + n] = f2bf(vv);
        else
          ((float*)Cv)[(size_t)m * N + n] = vv;
      }
    }
  }
}

// ---------------------------------------------------------------------------
// Low-rank forget gate -> LOG gate gk = log_sigmoid(z)/16 (bf16 in/out)
// ---------------------------------------------------------------------------
__global__ __launch_bounds__(256) void gk_kernel(const unsigned short* __restrict__ xn,
                                                 const float* __restrict__ Wgk1,
                                                 const float* __restrict__ Wgk2,
                                                 const float* __restrict__ bgk2,
                                                 unsigned short* __restrict__ gk) {
  int row = blockIdx.x;
  const unsigned short* xr = xn + (size_t)row * DD;
  int tid = threadIdx.x;

  float t16[16];
#pragma unroll
  for (int j = 0; j < 16; ++j) t16[j] = 0.0f;

#pragma unroll
  for (int dd = 0; dd < 4; ++dd) {
    int d = tid + dd * 256;
    float xv = bf2f(xr[d]);
    const float4* wrow = (const float4*)(Wgk1 + (size_t)d * 16);
#pragma unroll
    for (int q = 0; q < 4; ++q) {
      float4 wq = wrow[q];
      t16[q * 4 + 0] += xv * wq.x;
      t16[q * 4 + 1] += xv * wq.y;
      t16[q * 4 + 2] += xv * wq.z;
      t16[q * 4 + 3] += xv * wq.w;
    }
  }
#pragma unroll
  for (int j = 0; j < 16; ++j) {
    float s = t16[j];
#pragma unroll
    for (int o = 32; o > 0; o >>= 1) s += __shfl_down(s, o);
    t16[j] = s;
  }
  __shared__ float tmp[4][16];
  __shared__ float tf[16];
  int wid = tid >> 6;
  if ((tid & 63) == 0) {
#pragma unroll
    for (int j = 0; j < 16; ++j) tmp[wid][j] = t16[j];
  }
  __syncthreads();
  if (tid < 16) tf[tid] = tmp[0][tid] + tmp[1][tid] + tmp[2][tid] + tmp[3][tid];
  __syncthreads();

  float tl[16];
#pragma unroll
  for (int j = 0; j < 16; ++j) tl[j] = tf[j];

#pragma unroll
  for (int jj = 0; jj < 4; ++jj) {
    int n = tid * 4 + jj;
    float z = bgk2[n];
#pragma unroll
    for (int j = 0; j < 16; ++j) z += tl[j] * Wgk2[j * 1024 + n];
    float ls = fminf(z, 0.0f) - log1pf(expf(-fabsf(z)));
    gk[(size_t)row * 1024 + n] = f2bf(ls * (1.0f / 16.0f));
  }
}

// ---------------------------------------------------------------------------
// gate_chunk: per (b,h,chunk) block, 256 thr (one dk col each), bf16 in-place:
// q <- q*exp(cum)*scale; k <- k*exp(-cum); ebC = exp(cum_end) out (f32).
// ---------------------------------------------------------------------------
__global__ __launch_bounds__(256) void gate_chunk(const unsigned short* __restrict__ gk,
                                                  unsigned short* __restrict__ q,
                                                  unsigned short* __restrict__ k,
                                                  float* __restrict__ ebC) {
  int bid = blockIdx.x;
  int c = bid & 31;
  int h = (bid >> 5) & 3;
  int b = bid >> 7;
  int tid = threadIdx.x;
  size_t base = ((size_t)b * TT + c * CHK) * 1024 + h * 256 + tid;

  const float scale = 0.0625f;
  float cum = 0.0f;
  for (int t = 0; t < CHK; ++t) {
    size_t a = base + (size_t)t * 1024;
    cum += bf2f(gk[a]);
    q[a] = f2bf(bf2f(q[a]) * expf(cum) * scale);
    k[a] = f2bf(bf2f(k[a]) * expf(-cum));
  }
  ebC[((b * 4 + h) * NCHK + c) * 256 + tid] = expf(cum);
}

// ---------------------------------------------------------------------------
// trans_kernel: [B*T, H*256] slice -> T-major [bh][256][2048]; WITHE folds ebC
// ---------------------------------------------------------------------------
template <int WITHE>
__global__ __launch_bounds__(256) void trans_kernel(const unsigned short* __restrict__ in,
                                                    const float* __restrict__ ebC,
                                                    unsigned short* __restrict__ outT) {
  __shared__ unsigned short T[64][68];
  int bid = blockIdx.x;
  int dkt = bid & 3;
  int ct = (bid >> 2) & 31;
  int bh = bid >> 7;
  int b = bh >> 2, h = bh & 3;
  int tid = threadIdx.x;
  int r = tid >> 4;            // 0..15
  int c4 = (tid & 15) * 4;
  size_t srcbase = ((size_t)b * TT + ct * 64) * 1024 + h * 256 + dkt * 64;
#pragma unroll
  for (int i = 0; i < 4; ++i)
    *(ushort4*)&T[r + i * 16][c4] =
        *(const ushort4*)&in[srcbase + (size_t)(r + i * 16) * 1024 + c4];
  __syncthreads();
  size_t outbase = (size_t)bh * 524288 + (size_t)(dkt * 64) * 2048 + ct * 64;
  const float* ep = ebC + ((size_t)bh * 32 + ct) * 256 + dkt * 64;
#pragma unroll
  for (int i = 0; i < 4; ++i) {
    int dkl = r + i * 16;
    float e = WITHE ? ep[dkl] : 1.0f;
    ushort4 o;
    o.x = f2bf(bf2f(T[c4 + 0][dkl]) * e);
    o.y = f2bf(bf2f(T[c4 + 1][dkl]) * e);
    o.z = f2bf(bf2f(T[c4 + 2][dkl]) * e);
    o.w = f2bf(bf2f(T[c4 + 3][dkl]) * e);
    *(ushort4*)&outT[outbase + (size_t)dkl * 2048 + c4] = o;
  }
}

// ---------------------------------------------------------------------------
// u_gemm: per (bh,c,tile): UT_c[128dv x 128dk] = vT_slice @ khatT_slice^T,K=64
// (A=vT rows=dv, Bt=khatT rows=dk -> writes U TRANSPOSED [dv][dk])
// ---------------------------------------------------------------------------
__global__ __launch_bounds__(256) void u_gemm(const unsigned short* __restrict__ khatT,
                                              const unsigned short* __restrict__ vT,
                                              unsigned short* __restrict__ UT) {
  __shared__ unsigned short As[128 * 64];
  __shared__ unsigned short Bs[128 * 64];
  int tid = threadIdx.x;
  int bid = blockIdx.x;
  int tile = bid & 3;
  int bhc = bid >> 2;  // bh*32 + c
  int bh = bhc >> 5, c = bhc & 31;
  int m0 = (tile >> 1) * 128, n0 = (tile & 1) * 128;
  const unsigned short* Ab = vT + (size_t)bh * 524288 + c * 64;     // rows=dv
  const unsigned short* Bb = khatT + (size_t)bh * 524288 + c * 64;  // rows=dk
  unsigned short* Cb = UT + (size_t)bhc * 65536;

  int lane = tid & 63;
  int w64 = tid & 192;
  int wid = tid >> 6;
  int wm = (wid >> 1) * 64, wn = (wid & 1) * 64;
  int fr = lane & 15, fq = lane >> 4;

  f32x4 acc[4][4] = {};

#pragma unroll
  for (int j = 0; j < 4; ++j) {
    int gl = j * 256 + tid;
    int row = gl >> 3;
    int gs = (gl & 7) ^ (row & 7);
    gload16(&Ab[(size_t)(m0 + row) * 2048 + gs * 8],
            &As[(size_t)(j * 256 + w64) * 8]);
    gload16(&Bb[(size_t)(n0 + row) * 2048 + gs * 8],
            &Bs[(size_t)(j * 256 + w64) * 8]);
  }
  __syncthreads();

#pragma unroll
  for (int ph = 0; ph < 2; ++ph) {
    bf16x8 af[4], bv[4];
#pragma unroll
    for (int i = 0; i < 4; ++i) {
      int ra = wm + i * 16 + fr;
      af[i] = *(const bf16x8*)&As[ra * 64 + (((ph * 4 + fq) ^ (ra & 7)) * 8)];
      int rb = wn + i * 16 + fr;
      bv[i] = *(const bf16x8*)&Bs[rb * 64 + (((ph * 4 + fq) ^ (rb & 7)) * 8)];
    }
#pragma unroll
    for (int i = 0; i < 4; ++i)
#pragma unroll
      for (int jj = 0; jj < 4; ++jj)
        acc[i][jj] = __builtin_amdgcn_mfma_f32_16x16x32_bf16(af[i], bv[jj],
                                                             acc[i][jj], 0, 0, 0);
  }

  int col = lane & 15;
  int rbase = (lane >> 4) * 4;
#pragma unroll
  for (int i = 0; i < 4; ++i)
#pragma unroll
    for (int j = 0; j < 4; ++j) {
      int n = n0 + wn + j * 16 + col;
#pragma unroll
      for (int r = 0; r < 4; ++r) {
        int m = m0 + wm + i * 16 + rbase + r;
        Cb[(size_t)m * 256 + n] = f2bf(acc[i][j][r]);
      }
    }
}

// ---------------------------------------------------------------------------
// hscan: in-place UT -> HT (chunk-start states, [dv][dk] layout).
// grid = 16bh x 256dv; thread = dk.
// ---------------------------------------------------------------------------
__global__ __launch_bounds__(256) void hscan(unsigned short* __restrict__ UH,
                                             const float* __restrict__ ebC) {
  int bid = blockIdx.x;
  int bh = bid >> 8, dv = bid & 255;
  int tid = threadIdx.x;  // dk
  size_t base = ((size_t)bh * NCHK) * 65536 + (size_t)dv * 256 + tid;
  const float* ebb = ebC + (size_t)bh * NCHK * 256;
  float h = 0.0f;
  for (int c = 0; c < NCHK; ++c) {
    size_t a = base + (size_t)c * 65536;
    float u = bf2f(UH[a]);
    UH[a] = f2bf(h);
    h = ebb[c * 256 + tid] * h + u;
  }
}

// ---------------------------------------------------------------------------
// intra_mfma: per (bh,c): P = causal(q~ k~^T) via MFMA, park P bf16 in
// swizzled LDS, then O_intra = P @ V via MFMA (V from vT, B^T form).
// 4 waves: phase1 wave owns 16 t-rows; phase2 wave owns 64-dv panel.
// ---------------------------------------------------------------------------
__global__ __launch_bounds__(256) void intra_mfma(
    const unsigned short* __restrict__ qt, const unsigned short* __restrict__ kt,
    const unsigned short* __restrict__ vT, float* __restrict__ o) {
  __shared__ unsigned short QK[2][64 * 264];  // Qs, Ks ([64][264] pad rows)
  __shared__ unsigned short Sb[64 * 64];      // P bf16, XOR-swizzled
  unsigned short* Vs = &QK[0][0];             // overlay: [256][72] after phase1

  int bid = blockIdx.x;
  int c = bid & 31;
  int bh = bid >> 5;
  int b = bh >> 2, h = bh & 3;
  size_t rowbase = ((size_t)b * TT + c * 64) * 1024 + h * 256;
  size_t vtbase = (size_t)bh * 524288 + c * 64;
  int tid = threadIdx.x;
  int lane = tid & 63;
  int w = tid >> 6;
  int fr = lane & 15, fq = lane >> 4;

  // stage q~, k~ chunk tiles [64][256] -> [64][264]
#pragma unroll
  for (int i = 0; i < 8; ++i) {
    int g = tid + i * 256;       // 0..2047
    int row = g >> 5, gc = g & 31;
    *(bf16x8*)&QK[0][row * 264 + gc * 8] =
        *(const bf16x8*)&qt[rowbase + (size_t)row * 1024 + gc * 8];
    *(bf16x8*)&QK[1][row * 264 + gc * 8] =
        *(const bf16x8*)&kt[rowbase + (size_t)row * 1024 + gc * 8];
  }
  __syncthreads();

  // phase 1: P rows [w*16, w*16+16), cols all 64 (si=0..3), K=256
  {
    f32x4 accs[4] = {};
#pragma unroll
    for (int ks = 0; ks < 8; ++ks) {
      bf16x8 af = *(const bf16x8*)&QK[0][(w * 16 + fr) * 264 + ks * 32 + fq * 8];
#pragma unroll
      for (int si = 0; si < 4; ++si) {
        bf16x8 bf_ = *(const bf16x8*)&QK[1][(si * 16 + fr) * 264 + ks * 32 + fq * 8];
        accs[si] = __builtin_amdgcn_mfma_f32_16x16x32_bf16(af, bf_, accs[si], 0, 0, 0);
      }
    }
    // mask s<=t, write bf16 to swizzled Sb
#pragma unroll
    for (int si = 0; si < 4; ++si) {
#pragma unroll
      for (int r = 0; r < 4; ++r) {
        int t = w * 16 + fq * 4 + r;
        int s = si * 16 + fr;
        float val = (s <= t) ? accs[si][r] : 0.0f;
        int gS = s >> 3;
        Sb[t * 64 + ((gS ^ (t & 7)) * 8) + (s & 7)] = f2bf(val);
      }
    }
  }
  __syncthreads();

  // stage V slice [256 dv][64 s] from vT -> Vs [256][72]
#pragma unroll
  for (int i = 0; i < 8; ++i) {
    int g = tid + i * 256;       // 0..2047
    int dv = g >> 3, gc = g & 7;
    *(bf16x8*)&Vs[dv * 72 + gc * 8] =
        *(const bf16x8*)&vT[vtbase + (size_t)dv * 2048 + gc * 8];
  }
  __syncthreads();

  // phase 2: o[t][dv-panel w] = P @ V^T(form), K=64
  {
    int dv0 = w * 64;
    f32x4 acco[4][4] = {};
#pragma unroll
    for (int ks = 0; ks < 2; ++ks) {
      bf16x8 af[4], bv[4];
#pragma unroll
      for (int ti = 0; ti < 4; ++ti) {
        int t = ti * 16 + fr;
        af[ti] = *(const bf16x8*)&Sb[t * 64 + (((ks * 4 + fq) ^ (t & 7)) * 8)];
      }
#pragma unroll
      for (int nj = 0; nj < 4; ++nj)
        bv[nj] = *(const bf16x8*)&Vs[(dv0 + nj * 16 + fr) * 72 + ks * 32 + fq * 8];
#pragma unroll
      for (int ti = 0; ti < 4; ++ti)
#pragma unroll
        for (int nj = 0; nj < 4; ++nj)
          acco[ti][nj] = __builtin_amdgcn_mfma_f32_16x16x32_bf16(af[ti], bv[nj],
                                                                 acco[ti][nj], 0, 0, 0);
    }
#pragma unroll
    for (int ti = 0; ti < 4; ++ti)
#pragma unroll
      for (int nj = 0; nj < 4; ++nj)
#pragma unroll
        for (int r = 0; r < 4; ++r) {
          int t = ti * 16 + fq * 4 + r;
          int dv = dv0 + nj * 16 + fr;
          o[rowbase + (size_t)t * 1024 + dv] = acco[ti][nj][r];
        }
  }
}

// ---------------------------------------------------------------------------
// inter_mfma: per (bh,c): o += q~_chunk[64][256] @ H_c (HT [dv][dk] = B^T form)
// 4 waves: wave owns 64-dv panel; K=256 in 4 steps of 64.
// ---------------------------------------------------------------------------
__global__ __launch_bounds__(256) void inter_mfma(
    const unsigned short* __restrict__ qt, const unsigned short* __restrict__ HT,
    float* __restrict__ o) {
  __shared__ unsigned short Qs[64 * 264];
  __shared__ unsigned short Hs[256 * 72];
  int bid = blockIdx.x;
  int c = bid & 31;
  int bh = bid >> 5;
  int b = bh >> 2, h = bh & 3;
  size_t rowbase = ((size_t)b * TT + c * 64) * 1024 + h * 256;
  size_t htbase = ((size_t)(bh * 32 + c)) * 65536;
  int tid = threadIdx.x;
  int lane = tid & 63;
  int w = tid >> 6;
  int fr = lane & 15, fq = lane >> 4;
  int dv0 = w * 64;

  // stage q~ chunk [64][256]
#pragma unroll
  for (int i = 0; i < 8; ++i) {
    int g = tid + i * 256;
    int row = g >> 5, gc = g & 31;
    *(bf16x8*)&Qs[row * 264 + gc * 8] =
        *(const bf16x8*)&qt[rowbase + (size_t)row * 1024 + gc * 8];
  }

  f32x4 acc[4][4] = {};
  for (int k4 = 0; k4 < 4; ++k4) {
    __syncthreads();
    // stage HT slice [256 dv][64 dk]
#pragma unroll
    for (int i = 0; i < 8; ++i) {
      int g = tid + i * 256;
      int dv = g >> 3, gc = g & 7;
      *(bf16x8*)&Hs[dv * 72 + gc * 8] =
          *(const bf16x8*)&HT[htbase + (size_t)dv * 256 + k4 * 64 + gc * 8];
    }
    __syncthreads();
#pragma unroll
    for (int ks = 0; ks < 2; ++ks) {
      bf16x8 af[4], bv[4];
#pragma unroll
      for (int ti = 0; ti < 4; ++ti)
        af[ti] = *(const bf16x8*)&Qs[(ti * 16 + fr) * 264 + k4 * 64 + ks * 32 + fq * 8];
#pragma unroll
      for (int nj = 0; nj < 4; ++nj)
        bv[nj] = *(const bf16x8*)&Hs[(dv0 + nj * 16 + fr) * 72 + ks * 32 + fq * 8];
#pragma unroll
      for (int ti = 0; ti < 4; ++ti)
#pragma unroll
        for (int nj = 0; nj < 4; ++nj)
          acc[ti][nj] = __builtin_amdgcn_mfma_f32_16x16x32_bf16(af[ti], bv[nj],
                                                                acc[ti][nj], 0, 0, 0);
    }
  }

#pragma unroll
  for (int ti = 0; ti < 4; ++ti)
#pragma unroll
    for (int nj = 0; nj < 4; ++nj)
#pragma unroll
      for (int r = 0; r < 4; ++r) {
        int t = ti * 16 + fq * 4 + r;
        int dv = dv0 + nj * 16 + fr;
        size_t a = rowbase + (size_t)t * 1024 + dv;
        o[a] += acc[ti][nj][r];
      }
}

// ---------------------------------------------------------------------------
// Gated RMSNorm: o f32, g bf16 -> og bf16
// ---------------------------------------------------------------------------
__global__ __launch_bounds__(256) void grms_kernel(const float* __restrict__ o,
                                                   const unsigned short* __restrict__ g,
                                                   const float* __restrict__ rw,
                                                   unsigned short* __restrict__ og) {
  size_t base = (size_t)blockIdx.x * 256;
  int tid = threadIdx.x;
  float ov = o[base + tid];
  float s = ov * ov;
#pragma unroll
  for (int off = 32; off > 0; off >>= 1) s += __shfl_down(s, off);
  __shared__ float red[4];
  int wid = tid >> 6;
  if ((tid & 63) == 0) red[wid] = s;
  __syncthreads();
  float ms = (red[0] + red[1] + red[2] + red[3]) * (1.0f / 256.0f);
  float gv = bf2f(g[base + tid]);
  float sw = gv / (1.0f + expf(-gv));
  og[base + tid] = f2bf(ov * rsqrtf(ms + 1e-5f) * rw[tid] * sw);
}

// ---------------------------------------------------------------------------
extern "C" void kernel_launch(void* const* d_in, const int* in_sizes, int n_in,
                              void* d_out, int out_size, void* d_ws,
                              size_t ws_size, hipStream_t stream) {
  const float* x = (const float*)d_in[0];
  const float* ln1_w = (const float*)d_in[1];
  const float* ln1_b = (const float*)d_in[2];
  const float* Wq = (const float*)d_in[3];
  const float* Wk = (const float*)d_in[4];
  const float* Wv = (const float*)d_in[5];
  const float* Wg = (const float*)d_in[6];
  const float* Wgk1 = (const float*)d_in[7];
  const float* Wgk2 = (const float*)d_in[8];
  const float* bgk2 = (const float*)d_in[9];
  const float* rms_w = (const float*)d_in[10];
  const float* Wo = (const float*)d_in[11];
  const float* ln2_w = (const float*)d_in[12];
  const float* ln2_b = (const float*)d_in[13];
  const float* W1 = (const float*)d_in[14];
  const float* b1 = (const float*)d_in[15];
  const float* W2 = (const float*)d_in[16];
  const float* b2 = (const float*)d_in[17];
  float* out = (float*)d_out;

  const size_t S = (size_t)RR * DD;  // 8388608 elements
  unsigned short* actb = (unsigned short*)d_ws;  // xn -> vT -> og/xn2
  unsigned short* qb = actb + S;                 // q~
  unsigned short* kb = qb + S;                   // k~
  unsigned short* vb = kb + S;                   // v
  unsigned short* gb = vb + S;                   // g
  unsigned short* gkb = gb + S;                  // gk -> khatT
  float* ofs = (float*)(gkb + S);                // o (f32, S)
  unsigned short* UH = (unsigned short*)(ofs + S);  // UT -> HT, 4S bf16
  float* ebC = (float*)(UH + 4 * S);             // 131072 f32
  unsigned short* Wqt = (unsigned short*)(ebC + 131072);
  unsigned short* Wkt = Wqt + 1048576;
  unsigned short* Wvt = Wkt + 1048576;
  unsigned short* Wgt = Wvt + 1048576;
  unsigned short* Wot = Wgt + 1048576;
  unsigned short* W1t = Wot + 1048576;
  unsigned short* W2t = W1t + 3145728;
  // overlays:
  unsigned short* khatT = gkb;   // after gate_chunk, gk dead
  unsigned short* vT = actb;     // after gk_kernel, xn dead
  float* x1 = (float*)kb;        // f32 S over kb+vb (dead after intra)
  unsigned short* hb = UH;       // MLP hidden 3S bf16 (UH dead after inter)

  dim3 blk(256);

  // 0. weight transposes
  transpose_cast<<<dim3(32, 32), blk, 0, stream>>>(Wq, Wqt, 1024, 1024);
  transpose_cast<<<dim3(32, 32), blk, 0, stream>>>(Wk, Wkt, 1024, 1024);
  transpose_cast<<<dim3(32, 32), blk, 0, stream>>>(Wv, Wvt, 1024, 1024);
  transpose_cast<<<dim3(32, 32), blk, 0, stream>>>(Wg, Wgt, 1024, 1024);
  transpose_cast<<<dim3(32, 32), blk, 0, stream>>>(Wo, Wot, 1024, 1024);
  transpose_cast<<<dim3(96, 32), blk, 0, stream>>>(W1, W1t, 1024, 3072);
  transpose_cast<<<dim3(32, 96), blk, 0, stream>>>(W2, W2t, 3072, 1024);

  // 1. xn = LN(x)
  ln_kernel<<<RR, blk, 0, stream>>>(x, ln1_w, ln1_b, actb);

  // 2. projections
  dim3 g1024(1024 / 128, RR / 128);
  gemm_bf16<0, 1><<<g1024, blk, 0, stream>>>(actb, Wqt, nullptr, nullptr, qb, RR, 1024, 1024);
  gemm_bf16<0, 1><<<g1024, blk, 0, stream>>>(actb, Wkt, nullptr, nullptr, kb, RR, 1024, 1024);
  gemm_bf16<0, 1><<<g1024, blk, 0, stream>>>(actb, Wvt, nullptr, nullptr, vb, RR, 1024, 1024);
  gemm_bf16<0, 1><<<g1024, blk, 0, stream>>>(actb, Wgt, nullptr, nullptr, gb, RR, 1024, 1024);

  // 3. gk -> gkb
  gk_kernel<<<RR, blk, 0, stream>>>(actb, Wgk1, Wgk2, bgk2, gkb);

  // 4. gate transforms (in-place q,k), ebC
  gate_chunk<<<BB * HH * NCHK, blk, 0, stream>>>(gkb, qb, kb, ebC);

  // 5. transposes: khatT (ebC folded) over gkb; vT over actb
  trans_kernel<1><<<16 * 32 * 4, blk, 0, stream>>>(kb, ebC, khatT);
  trans_kernel<0><<<16 * 32 * 4, blk, 0, stream>>>(vb, ebC, vT);

  // 6. UT_c = (khat^T v)^T (MFMA) -> UH ; in-place scan -> HT
  u_gemm<<<16 * NCHK * 4, blk, 0, stream>>>(khatT, vT, UH);
  hscan<<<16 * 256, blk, 0, stream>>>(UH, ebC);

  // 7. intra-chunk (MFMA) -> ofs ; inter adds q~ @ H_c (MFMA)
  intra_mfma<<<16 * NCHK, blk, 0, stream>>>(qb, kb, vT, ofs);
  inter_mfma<<<16 * NCHK, blk, 0, stream>>>(qb, UH, ofs);

  // 8. og = gated rmsnorm -> actb (vT dead)
  grms_kernel<<<RR * HH, blk, 0, stream>>>(ofs, gb, rms_w, actb);

  // 9. x1 = x + og @ Wo
  gemm_bf16<3, 0><<<g1024, blk, 0, stream>>>(actb, Wot, nullptr, x, x1, RR, 1024, 1024);

  // 10. xn2 = LN(x1) -> actb
  ln_kernel<<<RR, blk, 0, stream>>>(x1, ln2_w, ln2_b, actb);

  // 11. h = (leaky_relu(xn2@W1+b1))^2 -> hb (over UH)
  dim3 g3072(3072 / 128, RR / 128);
  gemm_bf16<2, 1><<<g3072, blk, 0, stream>>>(actb, W1t, b1, nullptr, hb, RR, 3072, 1024);

  // 12. out = x1 + h @ W2 + b2
  gemm_bf16<4, 0><<<g1024, blk, 0, stream>>>(hb, W2t, b2, x1, out, RR, 1024, 3072);
}

// Round 7
// 474.353 us; speedup vs baseline: 10.1136x; 1.0491x over previous
//
#include <hip/hip_runtime.h>
#include <math.h>

// Problem constants
#define BB 4
#define TT 2048
#define DD 1024
#define HH 4
#define DK 256
#define DV 256
#define RR 8192
#define CHK 64
#define NCHK 32
#define SS ((size_t)RR * DD)

typedef __bf16 bf16x8 __attribute__((ext_vector_type(8)));
typedef float f32x4 __attribute__((ext_vector_type(4)));

static __device__ inline unsigned short f2bf(float f) {
  unsigned int u = __float_as_uint(f);
  unsigned int r = (u + 0x7fffu + ((u >> 16) & 1u)) >> 16;
  return (unsigned short)r;
}
static __device__ inline float bf2f(unsigned short h) {
  return __uint_as_float(((unsigned int)h) << 16);
}

// async global->LDS, 16B per lane; dest = wave-uniform base + lane*16
static __device__ __forceinline__ void gload16(const unsigned short* g,
                                               unsigned short* l) {
  __builtin_amdgcn_global_load_lds(
      (const __attribute__((address_space(1))) void*)g,
      (__attribute__((address_space(3))) void*)l, 16, 0, 0);
}

// ---------------------------------------------------------------------------
// LayerNorm: one block (256 thr) per row of D=1024. f32 in -> bf16 out.
// ---------------------------------------------------------------------------
__global__ __launch_bounds__(256) void ln_kernel(const float* __restrict__ x,
                                                 const float* __restrict__ w,
                                                 const float* __restrict__ b,
                                                 unsigned short* __restrict__ yb) {
  int row = blockIdx.x;
  const float* xr = x + (size_t)row * DD;
  unsigned short* ybr = yb + (size_t)row * DD;
  int tid = threadIdx.x;

  float4 v = ((const float4*)xr)[tid];
  float s = v.x + v.y + v.z + v.w;
  float ss = v.x * v.x + v.y * v.y + v.z * v.z + v.w * v.w;
#pragma unroll
  for (int o = 32; o > 0; o >>= 1) {
    s += __shfl_down(s, o);
    ss += __shfl_down(ss, o);
  }
  __shared__ float ls[4], lss[4];
  int wid = tid >> 6;
  if ((tid & 63) == 0) { ls[wid] = s; lss[wid] = ss; }
  __syncthreads();
  float sum = ls[0] + ls[1] + ls[2] + ls[3];
  float sumsq = lss[0] + lss[1] + lss[2] + lss[3];
  float mu = sum * (1.0f / DD);
  float var = sumsq * (1.0f / DD) - mu * mu;
  float rs = rsqrtf(var + 1e-5f);

  float4 wv = ((const float4*)w)[tid];
  float4 bv = ((const float4*)b)[tid];
  ushort4 ob;
  ob.x = f2bf((v.x - mu) * rs * wv.x + bv.x);
  ob.y = f2bf((v.y - mu) * rs * wv.y + bv.y);
  ob.z = f2bf((v.z - mu) * rs * wv.z + bv.z);
  ob.w = f2bf((v.w - mu) * rs * wv.w + bv.w);
  ((ushort4*)ybr)[tid] = ob;
}

// ---------------------------------------------------------------------------
// Weight transpose + cast: W [K,N] f32 -> Wt [N,K] bf16
// ---------------------------------------------------------------------------
__global__ __launch_bounds__(256) void transpose_cast(const float* __restrict__ W,
                                                      unsigned short* __restrict__ Wt,
                                                      int K, int N) {
  __shared__ float t[32][33];
  int k0 = blockIdx.y * 32, n0 = blockIdx.x * 32;
  int tid = threadIdx.x;
  int tx = tid & 31, ty = tid >> 5;  // ty 0..7
#pragma unroll
  for (int i = 0; i < 4; ++i)
    t[ty + i * 8][tx] = W[(size_t)(k0 + ty + i * 8) * N + n0 + tx];
  __syncthreads();
#pragma unroll
  for (int i = 0; i < 4; ++i)
    Wt[(size_t)(n0 + ty + i * 8) * K + k0 + tx] = f2bf(t[tx][ty + i * 8]);
}

// ---------------------------------------------------------------------------
// bf16 MFMA GEMM: C[M,N] = A[M,K] @ Bt[N,K]^T  (+epilogue)
// 128x128 tile, BK=64, DOUBLE-BUFFERED global_load_lds staging (prefetch
// next K-tile before computing current), XOR-swizzled LDS, XCD block swizzle.
// EPI: 0 none, 2 +bias,(leaky)^2, 3 +res, 4 +bias+res,
//      5 proj fan-out: write bf16 to Cv[(n>>10)*SS + m*1024 + (n&1023)]
// OUTBF: bf16 vs f32 output.
// ---------------------------------------------------------------------------
template <int EPI, int OUTBF>
__global__ __launch_bounds__(256) void gemm_bf16(
    const unsigned short* __restrict__ A,   // [M,K] bf16
    const unsigned short* __restrict__ Bt,  // [N,K] bf16
    const float* __restrict__ bias, const float* __restrict__ Res,
    void* __restrict__ Cv, int M, int N, int K) {
  __shared__ unsigned short As[2][128 * 64];  // [buf][row][64 bf16]
  __shared__ unsigned short Bs[2][128 * 64];
  int tid = threadIdx.x;
  // XCD-aware swizzle: contiguous chunk of wgs per XCD (nwg % 8 == 0)
  int nwg = gridDim.x * gridDim.y;
  int wg = blockIdx.y * gridDim.x + blockIdx.x;
  int cpx = nwg >> 3;
  wg = (wg & 7) * cpx + (wg >> 3);
  int m0 = (wg / gridDim.x) * 128, n0 = (wg % gridDim.x) * 128;
  int lane = tid & 63;
  int w64 = tid & 192;  // wave * 64
  int wid = tid >> 6;
  int wm = (wid >> 1) * 64, wn = (wid & 1) * 64;
  int fr = lane & 15, fq = lane >> 4;

  f32x4 acc[4][4] = {};

  auto STAGE = [&](int buf, int k0) {
#pragma unroll
    for (int j = 0; j < 4; ++j) {
      int gl = j * 256 + tid;           // granule 0..1023
      int row = gl >> 3;
      int gs = (gl & 7) ^ (row & 7);    // inverse-swizzled source granule
      gload16(&A[(size_t)(m0 + row) * K + k0 + gs * 8],
              &As[buf][(size_t)(j * 256 + w64) * 8]);
      gload16(&Bt[(size_t)(n0 + row) * K + k0 + gs * 8],
              &Bs[buf][(size_t)(j * 256 + w64) * 8]);
    }
  };

  STAGE(0, 0);
  asm volatile("s_waitcnt vmcnt(0)");
  __syncthreads();

  int cur = 0;
  for (int k0 = 0; k0 < K; k0 += 64) {
    if (k0 + 64 < K) STAGE(cur ^ 1, k0 + 64);  // prefetch next tile

#pragma unroll
    for (int ph = 0; ph < 2; ++ph) {
      bf16x8 af[4], bv[4];
#pragma unroll
      for (int i = 0; i < 4; ++i) {
        int ra = wm + i * 16 + fr;
        af[i] = *(const bf16x8*)&As[cur][ra * 64 + (((ph * 4 + fq) ^ (ra & 7)) * 8)];
        int rb = wn + i * 16 + fr;
        bv[i] = *(const bf16x8*)&Bs[cur][rb * 64 + (((ph * 4 + fq) ^ (rb & 7)) * 8)];
      }
#pragma unroll
      for (int i = 0; i < 4; ++i)
#pragma unroll
        for (int jj = 0; jj < 4; ++jj)
          acc[i][jj] = __builtin_amdgcn_mfma_f32_16x16x32_bf16(af[i], bv[jj],
                                                               acc[i][jj], 0, 0, 0);
    }
    __syncthreads();  // drains vmcnt -> prefetched tile visible; buffers safe
    cur ^= 1;
  }

  // epilogue: C/D layout col=lane&15, row=(lane>>4)*4+r
  int col = lane & 15;
  int rbase = (lane >> 4) * 4;
#pragma unroll
  for (int i = 0; i < 4; ++i) {
#pragma unroll
    for (int j = 0; j < 4; ++j) {
      int n = n0 + wn + j * 16 + col;
      float bvv = (EPI == 2 || EPI == 4) ? bias[n] : 0.0f;
#pragma unroll
      for (int r = 0; r < 4; ++r) {
        int m = m0 + wm + i * 16 + rbase + r;
        float vv = acc[i][j][r] + bvv;
        if (EPI == 2) {
          float t = vv > 0.0f ? vv : 0.01f * vv;
          vv = t * t;
        }
        if (EPI == 3 || EPI == 4) vv += Res[(size_t)m * N + n];
        if (EPI == 5) {
          ((unsigned short*)Cv)[(size_t)(n >> 10) * SS + (size_t)m * 1024 +
                                (n & 1023)] = f2bf(vv);
        } else if (OUTBF) {
          ((unsigned short*)Cv)[(size_t)m * N + n] = f2bf(vv);
        } else {
          ((float*)Cv)[(size_t)m * N + n] = vv;
        }
      }
    }
  }
}

// ---------------------------------------------------------------------------
// Low-rank forget gate -> LOG gate gk = log_sigmoid(z)/16 (bf16 in/out)
// ---------------------------------------------------------------------------
__global__ __launch_bounds__(256) void gk_kernel(const unsigned short* __restrict__ xn,
                                                 const float* __restrict__ Wgk1,
                                                 const float* __restrict__ Wgk2,
                                                 const float* __restrict__ bgk2,
                                                 unsigned short* __restrict__ gk) {
  int row = blockIdx.x;
  const unsigned short* xr = xn + (size_t)row * DD;
  int tid = threadIdx.x;

  float t16[16];
#pragma unroll
  for (int j = 0; j < 16; ++j) t16[j] = 0.0f;

#pragma unroll
  for (int dd = 0; dd < 4; ++dd) {
    int d = tid + dd * 256;
    float xv = bf2f(xr[d]);
    const float4* wrow = (const float4*)(Wgk1 + (size_t)d * 16);
#pragma unroll
    for (int q = 0; q < 4; ++q) {
      float4 wq = wrow[q];
      t16[q * 4 + 0] += xv * wq.x;
      t16[q * 4 + 1] += xv * wq.y;
      t16[q * 4 + 2] += xv * wq.z;
      t16[q * 4 + 3] += xv * wq.w;
    }
  }
#pragma unroll
  for (int j = 0; j < 16; ++j) {
    float s = t16[j];
#pragma unroll
    for (int o = 32; o > 0; o >>= 1) s += __shfl_down(s, o);
    t16[j] = s;
  }
  __shared__ float tmp[4][16];
  __shared__ float tf[16];
  int wid = tid >> 6;
  if ((tid & 63) == 0) {
#pragma unroll
    for (int j = 0; j < 16; ++j) tmp[wid][j] = t16[j];
  }
  __syncthreads();
  if (tid < 16) tf[tid] = tmp[0][tid] + tmp[1][tid] + tmp[2][tid] + tmp[3][tid];
  __syncthreads();

  float tl[16];
#pragma unroll
  for (int j = 0; j < 16; ++j) tl[j] = tf[j];

#pragma unroll
  for (int jj = 0; jj < 4; ++jj) {
    int n = tid * 4 + jj;
    float z = bgk2[n];
#pragma unroll
    for (int j = 0; j < 16; ++j) z += tl[j] * Wgk2[j * 1024 + n];
    float ls = fminf(z, 0.0f) - log1pf(expf(-fabsf(z)));
    gk[(size_t)row * 1024 + n] = f2bf(ls * (1.0f / 16.0f));
  }
}

// ---------------------------------------------------------------------------
// gate_chunk: per (b,h,chunk) block, 256 thr (one dk col each), bf16 in-place:
// q <- q*exp(cum)*scale; k <- k*exp(-cum); ebC = exp(cum_end) out (f32).
// ---------------------------------------------------------------------------
__global__ __launch_bounds__(256) void gate_chunk(const unsigned short* __restrict__ gk,
                                                  unsigned short* __restrict__ q,
                                                  unsigned short* __restrict__ k,
                                                  float* __restrict__ ebC) {
  int bid = blockIdx.x;
  int c = bid & 31;
  int h = (bid >> 5) & 3;
  int b = bid >> 7;
  int tid = threadIdx.x;
  size_t base = ((size_t)b * TT + c * CHK) * 1024 + h * 256 + tid;

  const float scale = 0.0625f;
  float cum = 0.0f;
  for (int t = 0; t < CHK; ++t) {
    size_t a = base + (size_t)t * 1024;
    cum += bf2f(gk[a]);
    q[a] = f2bf(bf2f(q[a]) * expf(cum) * scale);
    k[a] = f2bf(bf2f(k[a]) * expf(-cum));
  }
  ebC[((b * 4 + h) * NCHK + c) * 256 + tid] = expf(cum);
}

// ---------------------------------------------------------------------------
// trans_kernel: [B*T, H*256] slice -> T-major [bh][256][2048]; WITHE folds ebC
// ---------------------------------------------------------------------------
template <int WITHE>
__global__ __launch_bounds__(256) void trans_kernel(const unsigned short* __restrict__ in,
                                                    const float* __restrict__ ebC,
                                                    unsigned short* __restrict__ outT) {
  __shared__ unsigned short T[64][68];
  int bid = blockIdx.x;
  int dkt = bid & 3;
  int ct = (bid >> 2) & 31;
  int bh = bid >> 7;
  int b = bh >> 2, h = bh & 3;
  int tid = threadIdx.x;
  int r = tid >> 4;            // 0..15
  int c4 = (tid & 15) * 4;
  size_t srcbase = ((size_t)b * TT + ct * 64) * 1024 + h * 256 + dkt * 64;
#pragma unroll
  for (int i = 0; i < 4; ++i)
    *(ushort4*)&T[r + i * 16][c4] =
        *(const ushort4*)&in[srcbase + (size_t)(r + i * 16) * 1024 + c4];
  __syncthreads();
  size_t outbase = (size_t)bh * 524288 + (size_t)(dkt * 64) * 2048 + ct * 64;
  const float* ep = ebC + ((size_t)bh * 32 + ct) * 256 + dkt * 64;
#pragma unroll
  for (int i = 0; i < 4; ++i) {
    int dkl = r + i * 16;
    float e = WITHE ? ep[dkl] : 1.0f;
    ushort4 o;
    o.x = f2bf(bf2f(T[c4 + 0][dkl]) * e);
    o.y = f2bf(bf2f(T[c4 + 1][dkl]) * e);
    o.z = f2bf(bf2f(T[c4 + 2][dkl]) * e);
    o.w = f2bf(bf2f(T[c4 + 3][dkl]) * e);
    *(ushort4*)&outT[outbase + (size_t)dkl * 2048 + c4] = o;
  }
}

// ---------------------------------------------------------------------------
// u_gemm: per (bh,c,tile): UT_c[128dv x 128dk] = vT_slice @ khatT_slice^T,K=64
// ---------------------------------------------------------------------------
__global__ __launch_bounds__(256) void u_gemm(const unsigned short* __restrict__ khatT,
                                              const unsigned short* __restrict__ vT,
                                              unsigned short* __restrict__ UT) {
  __shared__ unsigned short As[128 * 64];
  __shared__ unsigned short Bs[128 * 64];
  int tid = threadIdx.x;
  int bid = blockIdx.x;
  int tile = bid & 3;
  int bhc = bid >> 2;  // bh*32 + c
  int bh = bhc >> 5, c = bhc & 31;
  int m0 = (tile >> 1) * 128, n0 = (tile & 1) * 128;
  const unsigned short* Ab = vT + (size_t)bh * 524288 + c * 64;     // rows=dv
  const unsigned short* Bb = khatT + (size_t)bh * 524288 + c * 64;  // rows=dk
  unsigned short* Cb = UT + (size_t)bhc * 65536;

  int lane = tid & 63;
  int w64 = tid & 192;
  int wid = tid >> 6;
  int wm = (wid >> 1) * 64, wn = (wid & 1) * 64;
  int fr = lane & 15, fq = lane >> 4;

  f32x4 acc[4][4] = {};

#pragma unroll
  for (int j = 0; j < 4; ++j) {
    int gl = j * 256 + tid;
    int row = gl >> 3;
    int gs = (gl & 7) ^ (row & 7);
    gload16(&Ab[(size_t)(m0 + row) * 2048 + gs * 8],
            &As[(size_t)(j * 256 + w64) * 8]);
    gload16(&Bb[(size_t)(n0 + row) * 2048 + gs * 8],
            &Bs[(size_t)(j * 256 + w64) * 8]);
  }
  __syncthreads();

#pragma unroll
  for (int ph = 0; ph < 2; ++ph) {
    bf16x8 af[4], bv[4];
#pragma unroll
    for (int i = 0; i < 4; ++i) {
      int ra = wm + i * 16 + fr;
      af[i] = *(const bf16x8*)&As[ra * 64 + (((ph * 4 + fq) ^ (ra & 7)) * 8)];
      int rb = wn + i * 16 + fr;
      bv[i] = *(const bf16x8*)&Bs[rb * 64 + (((ph * 4 + fq) ^ (rb & 7)) * 8)];
    }
#pragma unroll
    for (int i = 0; i < 4; ++i)
#pragma unroll
      for (int jj = 0; jj < 4; ++jj)
        acc[i][jj] = __builtin_amdgcn_mfma_f32_16x16x32_bf16(af[i], bv[jj],
                                                             acc[i][jj], 0, 0, 0);
  }

  int col = lane & 15;
  int rbase = (lane >> 4) * 4;
#pragma unroll
  for (int i = 0; i < 4; ++i)
#pragma unroll
    for (int j = 0; j < 4; ++j) {
      int n = n0 + wn + j * 16 + col;
#pragma unroll
      for (int r = 0; r < 4; ++r) {
        int m = m0 + wm + i * 16 + rbase + r;
        Cb[(size_t)m * 256 + n] = f2bf(acc[i][j][r]);
      }
    }
}

// ---------------------------------------------------------------------------
// hscan: in-place UT -> HT (chunk-start states, [dv][dk] layout).
// ---------------------------------------------------------------------------
__global__ __launch_bounds__(256) void hscan(unsigned short* __restrict__ UH,
                                             const float* __restrict__ ebC) {
  int bid = blockIdx.x;
  int bh = bid >> 8, dv = bid & 255;
  int tid = threadIdx.x;  // dk
  size_t base = ((size_t)bh * NCHK) * 65536 + (size_t)dv * 256 + tid;
  const float* ebb = ebC + (size_t)bh * NCHK * 256;
  float h = 0.0f;
  for (int c = 0; c < NCHK; ++c) {
    size_t a = base + (size_t)c * 65536;
    float u = bf2f(UH[a]);
    UH[a] = f2bf(h);
    h = ebb[c * 256 + tid] * h + u;
  }
}

// ---------------------------------------------------------------------------
// intra_mfma: per (bh,c): P = causal(q~ k~^T) via MFMA, park P bf16 in
// swizzled LDS, then O_intra = P @ V via MFMA (V from vT, B^T form).
// ---------------------------------------------------------------------------
__global__ __launch_bounds__(256) void intra_mfma(
    const unsigned short* __restrict__ qt, const unsigned short* __restrict__ kt,
    const unsigned short* __restrict__ vT, float* __restrict__ o) {
  __shared__ unsigned short QK[2][64 * 264];  // Qs, Ks ([64][264] pad rows)
  __shared__ unsigned short Sb[64 * 64];      // P bf16, XOR-swizzled
  unsigned short* Vs = &QK[0][0];             // overlay: [256][72] after phase1

  int bid = blockIdx.x;
  int c = bid & 31;
  int bh = bid >> 5;
  int b = bh >> 2, h = bh & 3;
  size_t rowbase = ((size_t)b * TT + c * 64) * 1024 + h * 256;
  size_t vtbase = (size_t)bh * 524288 + c * 64;
  int tid = threadIdx.x;
  int lane = tid & 63;
  int w = tid >> 6;
  int fr = lane & 15, fq = lane >> 4;

  // stage q~, k~ chunk tiles [64][256] -> [64][264]
#pragma unroll
  for (int i = 0; i < 8; ++i) {
    int g = tid + i * 256;       // 0..2047
    int row = g >> 5, gc = g & 31;
    *(bf16x8*)&QK[0][row * 264 + gc * 8] =
        *(const bf16x8*)&qt[rowbase + (size_t)row * 1024 + gc * 8];
    *(bf16x8*)&QK[1][row * 264 + gc * 8] =
        *(const bf16x8*)&kt[rowbase + (size_t)row * 1024 + gc * 8];
  }
  __syncthreads();

  // phase 1: P rows [w*16, w*16+16), cols all 64, K=256
  {
    f32x4 accs[4] = {};
#pragma unroll
    for (int ks = 0; ks < 8; ++ks) {
      bf16x8 af = *(const bf16x8*)&QK[0][(w * 16 + fr) * 264 + ks * 32 + fq * 8];
#pragma unroll
      for (int si = 0; si < 4; ++si) {
        bf16x8 bf_ = *(const bf16x8*)&QK[1][(si * 16 + fr) * 264 + ks * 32 + fq * 8];
        accs[si] = __builtin_amdgcn_mfma_f32_16x16x32_bf16(af, bf_, accs[si], 0, 0, 0);
      }
    }
#pragma unroll
    for (int si = 0; si < 4; ++si) {
#pragma unroll
      for (int r = 0; r < 4; ++r) {
        int t = w * 16 + fq * 4 + r;
        int s = si * 16 + fr;
        float val = (s <= t) ? accs[si][r] : 0.0f;
        int gS = s >> 3;
        Sb[t * 64 + ((gS ^ (t & 7)) * 8) + (s & 7)] = f2bf(val);
      }
    }
  }
  __syncthreads();

  // stage V slice [256 dv][64 s] from vT -> Vs [256][72]
#pragma unroll
  for (int i = 0; i < 8; ++i) {
    int g = tid + i * 256;       // 0..2047
    int dv = g >> 3, gc = g & 7;
    *(bf16x8*)&Vs[dv * 72 + gc * 8] =
        *(const bf16x8*)&vT[vtbase + (size_t)dv * 2048 + gc * 8];
  }
  __syncthreads();

  // phase 2: o[t][dv-panel w] = P @ V^T(form), K=64
  {
    int dv0 = w * 64;
    f32x4 acco[4][4] = {};
#pragma unroll
    for (int ks = 0; ks < 2; ++ks) {
      bf16x8 af[4], bv[4];
#pragma unroll
      for (int ti = 0; ti < 4; ++ti) {
        int t = ti * 16 + fr;
        af[ti] = *(const bf16x8*)&Sb[t * 64 + (((ks * 4 + fq) ^ (t & 7)) * 8)];
      }
#pragma unroll
      for (int nj = 0; nj < 4; ++nj)
        bv[nj] = *(const bf16x8*)&Vs[(dv0 + nj * 16 + fr) * 72 + ks * 32 + fq * 8];
#pragma unroll
      for (int ti = 0; ti < 4; ++ti)
#pragma unroll
        for (int nj = 0; nj < 4; ++nj)
          acco[ti][nj] = __builtin_amdgcn_mfma_f32_16x16x32_bf16(af[ti], bv[nj],
                                                                 acco[ti][nj], 0, 0, 0);
    }
#pragma unroll
    for (int ti = 0; ti < 4; ++ti)
#pragma unroll
      for (int nj = 0; nj < 4; ++nj)
#pragma unroll
        for (int r = 0; r < 4; ++r) {
          int t = ti * 16 + fq * 4 + r;
          int dv = dv0 + nj * 16 + fr;
          o[rowbase + (size_t)t * 1024 + dv] = acco[ti][nj][r];
        }
  }
}

// ---------------------------------------------------------------------------
// inter_mfma: per (bh,c): o += q~_chunk[64][256] @ H_c (HT [dv][dk] B^T form)
// ---------------------------------------------------------------------------
__global__ __launch_bounds__(256) void inter_mfma(
    const unsigned short* __restrict__ qt, const unsigned short* __restrict__ HT,
    float* __restrict__ o) {
  __shared__ unsigned short Qs[64 * 264];
  __shared__ unsigned short Hs[256 * 72];
  int bid = blockIdx.x;
  int c = bid & 31;
  int bh = bid >> 5;
  int b = bh >> 2, h = bh & 3;
  size_t rowbase = ((size_t)b * TT + c * 64) * 1024 + h * 256;
  size_t htbase = ((size_t)(bh * 32 + c)) * 65536;
  int tid = threadIdx.x;
  int lane = tid & 63;
  int w = tid >> 6;
  int fr = lane & 15, fq = lane >> 4;
  int dv0 = w * 64;

  // stage q~ chunk [64][256]
#pragma unroll
  for (int i = 0; i < 8; ++i) {
    int g = tid + i * 256;
    int row = g >> 5, gc = g & 31;
    *(bf16x8*)&Qs[row * 264 + gc * 8] =
        *(const bf16x8*)&qt[rowbase + (size_t)row * 1024 + gc * 8];
  }

  f32x4 acc[4][4] = {};
  for (int k4 = 0; k4 < 4; ++k4) {
    __syncthreads();
#pragma unroll
    for (int i = 0; i < 8; ++i) {
      int g = tid + i * 256;
      int dv = g >> 3, gc = g & 7;
      *(bf16x8*)&Hs[dv * 72 + gc * 8] =
          *(const bf16x8*)&HT[htbase + (size_t)dv * 256 + k4 * 64 + gc * 8];
    }
    __syncthreads();
#pragma unroll
    for (int ks = 0; ks < 2; ++ks) {
      bf16x8 af[4], bv[4];
#pragma unroll
      for (int ti = 0; ti < 4; ++ti)
        af[ti] = *(const bf16x8*)&Qs[(ti * 16 + fr) * 264 + k4 * 64 + ks * 32 + fq * 8];
#pragma unroll
      for (int nj = 0; nj < 4; ++nj)
        bv[nj] = *(const bf16x8*)&Hs[(dv0 + nj * 16 + fr) * 72 + ks * 32 + fq * 8];
#pragma unroll
      for (int ti = 0; ti < 4; ++ti)
#pragma unroll
        for (int nj = 0; nj < 4; ++nj)
          acc[ti][nj] = __builtin_amdgcn_mfma_f32_16x16x32_bf16(af[ti], bv[nj],
                                                                acc[ti][nj], 0, 0, 0);
    }
  }

#pragma unroll
  for (int ti = 0; ti < 4; ++ti)
#pragma unroll
    for (int nj = 0; nj < 4; ++nj)
#pragma unroll
      for (int r = 0; r < 4; ++r) {
        int t = ti * 16 + fq * 4 + r;
        int dv = dv0 + nj * 16 + fr;
        size_t a = rowbase + (size_t)t * 1024 + dv;
        o[a] += acc[ti][nj][r];
      }
}

// ---------------------------------------------------------------------------
// Gated RMSNorm: o f32, g bf16 -> og bf16
// ---------------------------------------------------------------------------
__global__ __launch_bounds__(256) void grms_kernel(const float* __restrict__ o,
                                                   const unsigned short* __restrict__ g,
                                                   const float* __restrict__ rw,
                                                   unsigned short* __restrict__ og) {
  size_t base = (size_t)blockIdx.x * 256;
  int tid = threadIdx.x;
  float ov = o[base + tid];
  float s = ov * ov;
#pragma unroll
  for (int off = 32; off > 0; off >>= 1) s += __shfl_down(s, off);
  __shared__ float red[4];
  int wid = tid >> 6;
  if ((tid & 63) == 0) red[wid] = s;
  __syncthreads();
  float ms = (red[0] + red[1] + red[2] + red[3]) * (1.0f / 256.0f);
  float gv = bf2f(g[base + tid]);
  float sw = gv / (1.0f + expf(-gv));
  og[base + tid] = f2bf(ov * rsqrtf(ms + 1e-5f) * rw[tid] * sw);
}

// ---------------------------------------------------------------------------
extern "C" void kernel_launch(void* const* d_in, const int* in_sizes, int n_in,
                              void* d_out, int out_size, void* d_ws,
                              size_t ws_size, hipStream_t stream) {
  const float* x = (const float*)d_in[0];
  const float* ln1_w = (const float*)d_in[1];
  const float* ln1_b = (const float*)d_in[2];
  const float* Wq = (const float*)d_in[3];
  const float* Wk = (const float*)d_in[4];
  const float* Wv = (const float*)d_in[5];
  const float* Wg = (const float*)d_in[6];
  const float* Wgk1 = (const float*)d_in[7];
  const float* Wgk2 = (const float*)d_in[8];
  const float* bgk2 = (const float*)d_in[9];
  const float* rms_w = (const float*)d_in[10];
  const float* Wo = (const float*)d_in[11];
  const float* ln2_w = (const float*)d_in[12];
  const float* ln2_b = (const float*)d_in[13];
  const float* W1 = (const float*)d_in[14];
  const float* b1 = (const float*)d_in[15];
  const float* W2 = (const float*)d_in[16];
  const float* b2 = (const float*)d_in[17];
  float* out = (float*)d_out;

  const size_t S = SS;  // 8388608 elements
  unsigned short* actb = (unsigned short*)d_ws;  // xn -> vT -> og/xn2
  unsigned short* qb = actb + S;                 // q~   (qkvg contiguous!)
  unsigned short* kb = qb + S;                   // k~
  unsigned short* vb = kb + S;                   // v
  unsigned short* gb = vb + S;                   // g
  unsigned short* gkb = gb + S;                  // gk -> khatT
  float* ofs = (float*)(gkb + S);                // o (f32, S)
  unsigned short* UH = (unsigned short*)(ofs + S);  // UT -> HT, 4S bf16
  float* ebC = (float*)(UH + 4 * S);             // 131072 f32
  unsigned short* Wqkvgt = (unsigned short*)(ebC + 131072);  // 4x 1M bf16
  unsigned short* Wot = Wqkvgt + 4194304;
  unsigned short* W1t = Wot + 1048576;
  unsigned short* W2t = W1t + 3145728;
  // overlays:
  unsigned short* khatT = gkb;   // after gate_chunk, gk dead
  unsigned short* vT = actb;     // after gk_kernel, xn dead
  float* x1 = (float*)kb;        // f32 S over kb+vb (dead after intra)
  unsigned short* hb = UH;       // MLP hidden 3S bf16 (UH dead after inter)

  dim3 blk(256);

  // 0. weight transposes (qkvg into one contiguous [4096][1024] block)
  transpose_cast<<<dim3(32, 32), blk, 0, stream>>>(Wq, Wqkvgt, 1024, 1024);
  transpose_cast<<<dim3(32, 32), blk, 0, stream>>>(Wk, Wqkvgt + 1048576, 1024, 1024);
  transpose_cast<<<dim3(32, 32), blk, 0, stream>>>(Wv, Wqkvgt + 2097152, 1024, 1024);
  transpose_cast<<<dim3(32, 32), blk, 0, stream>>>(Wg, Wqkvgt + 3145728, 1024, 1024);
  transpose_cast<<<dim3(32, 32), blk, 0, stream>>>(Wo, Wot, 1024, 1024);
  transpose_cast<<<dim3(96, 32), blk, 0, stream>>>(W1, W1t, 1024, 3072);
  transpose_cast<<<dim3(32, 96), blk, 0, stream>>>(W2, W2t, 3072, 1024);

  // 1. xn = LN(x)
  ln_kernel<<<RR, blk, 0, stream>>>(x, ln1_w, ln1_b, actb);

  // 2. merged q|k|v|g projection: N=4096, fan-out epilogue to qb..gb
  dim3 g4096(4096 / 128, RR / 128);
  gemm_bf16<5, 1><<<g4096, blk, 0, stream>>>(actb, Wqkvgt, nullptr, nullptr, qb,
                                             RR, 4096, 1024);

  // 3. gk -> gkb
  gk_kernel<<<RR, blk, 0, stream>>>(actb, Wgk1, Wgk2, bgk2, gkb);

  // 4. gate transforms (in-place q,k), ebC
  gate_chunk<<<BB * HH * NCHK, blk, 0, stream>>>(gkb, qb, kb, ebC);

  // 5. transposes: khatT (ebC folded) over gkb; vT over actb
  trans_kernel<1><<<16 * 32 * 4, blk, 0, stream>>>(kb, ebC, khatT);
  trans_kernel<0><<<16 * 32 * 4, blk, 0, stream>>>(vb, ebC, vT);

  // 6. UT_c = (khat^T v)^T (MFMA) -> UH ; in-place scan -> HT
  u_gemm<<<16 * NCHK * 4, blk, 0, stream>>>(khatT, vT, UH);
  hscan<<<16 * 256, blk, 0, stream>>>(UH, ebC);

  // 7. intra-chunk (MFMA) -> ofs ; inter adds q~ @ H_c (MFMA)
  intra_mfma<<<16 * NCHK, blk, 0, stream>>>(qb, kb, vT, ofs);
  inter_mfma<<<16 * NCHK, blk, 0, stream>>>(qb, UH, ofs);

  // 8. og = gated rmsnorm -> actb (vT dead)
  grms_kernel<<<RR * HH, blk, 0, stream>>>(ofs, gb, rms_w, actb);

  // 9. x1 = x + og @ Wo
  dim3 g1024(1024 / 128, RR / 128);
  gemm_bf16<3, 0><<<g1024, blk, 0, stream>>>(actb, Wot, nullptr, x, x1, RR, 1024, 1024);

  // 10. xn2 = LN(x1) -> actb
  ln_kernel<<<RR, blk, 0, stream>>>(x1, ln2_w, ln2_b, actb);

  // 11. h = (leaky_relu(xn2@W1+b1))^2 -> hb (over UH)
  dim3 g3072(3072 / 128, RR / 128);
  gemm_bf16<2, 1><<<g3072, blk, 0, stream>>>(actb, W1t, b1, nullptr, hb, RR, 3072, 1024);

  // 12. out = x1 + h @ W2 + b2
  gemm_bf16<4, 0><<<g1024, blk, 0, stream>>>(hb, W2t, b2, x1, out, RR, 1024, 3072);
}